// Round 1
// 1418.274 us; speedup vs baseline: 1.3613x; 1.3613x over previous
//
#include <hip/hip_runtime.h>
#include <hip/hip_bf16.h>

// ---------------------------------------------------------------------------
// BasicBlock (EfficientViT-style) on MI355X. Input dtype (fp32 vs bf16) is
// runtime-detected; all weights are pre-converted into a bf16 arena in ws so
// the compute kernels are dtype-free. GEMMs: bf16 MFMA, fp32 accum.
//
// Layouts:
//   CT = [C][N]  n-contiguous (N = 50176 = 64*784) fp32, residuals/attn in.
//   NK = [N][K]  k-contiguous bf16, MFMA GEMM operands (ds_read_b128 frags).
// ---------------------------------------------------------------------------

#define NPOS 50176                  // 64 * 784
#define NEL ((size_t)512 * NPOS)

typedef __hip_bfloat16 hbf;
typedef __attribute__((ext_vector_type(8))) short short8;   // 8 bf16
typedef __attribute__((ext_vector_type(4))) float f32x4;

__device__ __forceinline__ float hswish(float v) {
    float t = fminf(fmaxf(v + 3.0f, 0.0f), 6.0f);
    return v * t * (1.0f / 6.0f);
}
__device__ __forceinline__ float b2f(hbf x) { return __bfloat162float(x); }
__device__ __forceinline__ hbf f2b(float x) { return __float2bfloat16(x); }

__device__ __forceinline__ unsigned short bfb(float v) {
    hbf h = f2b(v); unsigned short u; __builtin_memcpy(&u, &h, 2); return u;
}
__device__ __forceinline__ unsigned pk2(float a, float b) {
    return (unsigned)bfb(a) | ((unsigned)bfb(b) << 16);
}
// byte address into a [row][64 bf16] (=128B rows) LDS array, XOR-swizzled so
// that column-slice ds_read_b128 across 16 lanes is ~2-way conflict free.
__device__ __forceinline__ int swz128(int row, int b) {
    return row * 128 + (b ^ ((row & 7) << 4));
}

// Probe x's dtype: low 16 bits of fp32 words are random mantissa bits (~16%
// "sane bf16 exponent" rate); in a packed-bf16 buffer they are real bf16
// values (~100%). 64 words, threshold 32 -> error prob < 1e-10.
__device__ __forceinline__ bool is_bf16_buf(const void* probe) {
    const unsigned* w = (const unsigned*)probe;
    int hits = 0;
#pragma unroll
    for (int i = 0; i < 64; i++) {
        unsigned lo = w[i] & 0xFFFFu;
        unsigned e = (lo >> 7) & 0xFFu;
        hits += ((e >= 100u && e <= 140u) || lo == 0u) ? 1 : 0;
    }
    return hits >= 32;
}

// ---------------------------------------------------------------------------
// Weight arena (bf16) — compile-time element offsets.
// ---------------------------------------------------------------------------
#define OFF_W01  0          // ffn0_w1 [1024][512]
#define OFF_W02  524288     // ffn0_w2 [512][1024]
#define OFF_W11  1048576    // ffn1_w1 [1024][512]
#define OFF_W12  1572864    // ffn1_w2 [512][1024]
#define OFF_PW   2097152    // proj_w  [512][512]
#define OFF_QKVW 2359296    // qkv_w   [8][96][64]
#define OFF_QKVB 2408448    // qkv_b   [8][96]
#define OFF_W7   2409216
#define OFF_B7   2410000
#define OFF_W5   2410016
#define OFF_B5   2410416
#define OFF_W3   2410432    // [6][16][9]
#define OFF_B3   2411296    // [6][16]
#define OFF_AB   2411392    // [8][49]
#define OFF_D0W  2411784    // dw0_w [512][9]
#define OFF_D0B  2416392
#define OFF_D1W  2416904
#define OFF_D1B  2421512
#define OFF_B01  2422024    // ffn0_b1 [1024]
#define OFF_B02  2423048
#define OFF_B11  2423560
#define OFF_B12  2424584
#define OFF_PB   2425096
#define ARENA_TOT 2425608

struct CvtArgs { const void* src; int off; int count; };
struct CvtTable { CvtArgs t[23]; };

__global__ __launch_bounds__(256) void k_convert(CvtTable tab, hbf* __restrict__ arena,
                                                 const void* __restrict__ probe) {
    bool isbf = is_bf16_buf(probe);
    CvtArgs a = tab.t[blockIdx.y];
    int i = blockIdx.x * 256 + threadIdx.x;
    if (i >= a.count) return;
    float v = isbf ? b2f(((const hbf*)a.src)[i]) : ((const float*)a.src)[i];
    arena[a.off + i] = f2b(v);
}

// ---------------------------------------------------------------------------
// MFMA GEMM: D[m][n] = A[m][:] . B[n][:]  (both k-contiguous rows, bf16)
// 128x128 tile, BK=32, 4 waves, 4x4 frags of mfma_f32_16x16x32_bf16.
// EPI: 0=HID  bf16 NK [m_sp][1024] = hswish(acc + bias[n])
//      1=Y2   f32 CT [m_och][NPOS] = acc + bias[m] + bf16resNK[n][512]
//      2=PROJ f32 CT [m_och][perm(n)] = acc + bias[m] + f32resCT[same]
//      3=OUT  NCHW (bf16 or f32 per probe) = acc + bias[m] + f32resCT
// ---------------------------------------------------------------------------
template <int EPI, int K>
__global__ __launch_bounds__(256) void k_gemm(const hbf* __restrict__ A,
                                              const hbf* __restrict__ B,
                                              const hbf* __restrict__ bias,
                                              const void* __restrict__ res,
                                              void* __restrict__ out,
                                              const void* __restrict__ probe) {
    __shared__ short sA[128 * 40];   // 32 k padded to 40 shorts (80 B rows)
    __shared__ short sB[128 * 40];

    const int tid = threadIdx.x;
    const int wave = tid >> 6, lane = tid & 63;
    const int col = lane & 15, quad = lane >> 4;
    const int m0 = blockIdx.x * 128, n0 = blockIdx.y * 128;
    const int wm = (wave & 1) * 64, wn = (wave >> 1) * 64;

    const int r0 = tid >> 2, c0 = tid & 3;
    const int r1 = 64 + (tid >> 2), c1 = tid & 3;

    f32x4 acc[4][4];
#pragma unroll
    for (int i = 0; i < 4; i++)
#pragma unroll
        for (int j = 0; j < 4; j++) acc[i][j] = (f32x4){0.f, 0.f, 0.f, 0.f};

    short8 pA0 = *(const short8*)(A + (size_t)(m0 + r0) * K + c0 * 8);
    short8 pA1 = *(const short8*)(A + (size_t)(m0 + r1) * K + c1 * 8);
    short8 pB0 = *(const short8*)(B + (size_t)(n0 + r0) * K + c0 * 8);
    short8 pB1 = *(const short8*)(B + (size_t)(n0 + r1) * K + c1 * 8);

    for (int k0 = 0; k0 < K; k0 += 32) {
        __syncthreads();
        *(short8*)(sA + r0 * 40 + c0 * 8) = pA0;
        *(short8*)(sA + r1 * 40 + c1 * 8) = pA1;
        *(short8*)(sB + r0 * 40 + c0 * 8) = pB0;
        *(short8*)(sB + r1 * 40 + c1 * 8) = pB1;
        if (k0 + 32 < K) {
            pA0 = *(const short8*)(A + (size_t)(m0 + r0) * K + k0 + 32 + c0 * 8);
            pA1 = *(const short8*)(A + (size_t)(m0 + r1) * K + k0 + 32 + c1 * 8);
            pB0 = *(const short8*)(B + (size_t)(n0 + r0) * K + k0 + 32 + c0 * 8);
            pB1 = *(const short8*)(B + (size_t)(n0 + r1) * K + k0 + 32 + c1 * 8);
        }
        __syncthreads();

        short8 af[4], bfr[4];
#pragma unroll
        for (int i = 0; i < 4; i++)
            af[i] = *(const short8*)(sA + (wm + i * 16 + col) * 40 + quad * 8);
#pragma unroll
        for (int j = 0; j < 4; j++)
            bfr[j] = *(const short8*)(sB + (wn + j * 16 + col) * 40 + quad * 8);
#pragma unroll
        for (int i = 0; i < 4; i++)
#pragma unroll
            for (int j = 0; j < 4; j++)
                acc[i][j] = __builtin_amdgcn_mfma_f32_16x16x32_bf16(af[i], bfr[j], acc[i][j], 0, 0, 0);
    }

    bool outbf = false;
    if constexpr (EPI == 3) outbf = is_bf16_buf(probe);

#pragma unroll
    for (int i = 0; i < 4; i++) {
#pragma unroll
        for (int j = 0; j < 4; j++) {
#pragma unroll
            for (int r = 0; r < 4; r++) {
                int mi = m0 + wm + i * 16 + quad * 4 + r;
                int nj = n0 + wn + j * 16 + col;
                float v = acc[i][j][r];
                if constexpr (EPI == 0) {
                    v = hswish(v + b2f(bias[nj]));
                    ((hbf*)out)[(size_t)mi * 1024 + nj] = f2b(v);
                } else if constexpr (EPI == 1) {
                    v += b2f(bias[mi]) + b2f(((const hbf*)res)[(size_t)nj * 512 + mi]);
                    ((float*)out)[(size_t)mi * NPOS + nj] = v;
                } else if constexpr (EPI == 2) {
                    int w = nj / 49, p = nj % 49;
                    int nct = (w >> 4) * 784 + (((w >> 2) & 3) * 7 + p / 7) * 28 + (w & 3) * 7 + p % 7;
                    size_t oi = (size_t)mi * NPOS + nct;
                    v += b2f(bias[mi]) + ((const float*)res)[oi];
                    ((float*)out)[oi] = v;
                } else {
                    int b = nj / 784, hw = nj % 784;
                    v += b2f(bias[mi]) + ((const float*)res)[(size_t)mi * NPOS + nj];
                    size_t oi = ((size_t)b * 512 + mi) * 784 + hw;
                    if (outbf) ((hbf*)out)[oi] = f2b(v);
                    else ((float*)out)[oi] = v;
                }
            }
        }
    }
}

// ---------------------------------------------------------------------------
// Depthwise 3x3 + residual, LDS-transposed to NK bf16 output.
// MODE 0: in = x NCHW (dtype per probe)  -> outNK
// MODE 1: in = x3f CT f32 -> outNK + outCT f32
// ---------------------------------------------------------------------------
template <int MODE, bool ISBF>
__device__ void dw_body(float (*tile)[65], const void* __restrict__ in,
                        const hbf* __restrict__ w, const hbf* __restrict__ bias,
                        hbf* __restrict__ outNK, float* __restrict__ outCT) {
    const int tid = threadIdx.x;
    const int tx = tid & 63, tg = tid >> 6;
    const int n0 = blockIdx.x * 64, c0 = blockIdx.y * 64;

    const int n = n0 + tx;
    const int b = n / 784, hw = n % 784;
    const int r = hw / 28, s = hw % 28;

    for (int cc = tg; cc < 64; cc += 4) {
        const int c = c0 + cc;
        float wv[9];
#pragma unroll
        for (int t = 0; t < 9; t++) wv[t] = b2f(w[c * 9 + t]);
        float acc = b2f(bias[c]);
        float center = 0.0f;
#pragma unroll
        for (int dy = -1; dy <= 1; dy++) {
            int rr = r + dy;
            if (rr < 0 || rr >= 28) continue;
#pragma unroll
            for (int dx = -1; dx <= 1; dx++) {
                int ss = s + dx;
                if (ss < 0 || ss >= 28) continue;
                float v;
                if constexpr (MODE == 0) {
                    size_t ix = ((size_t)b * 512 + c) * 784 + rr * 28 + ss;
                    v = ISBF ? b2f(((const hbf*)in)[ix]) : ((const float*)in)[ix];
                } else {
                    v = ((const float*)in)[(size_t)c * NPOS + (size_t)b * 784 + rr * 28 + ss];
                }
                acc += v * wv[(dy + 1) * 3 + (dx + 1)];
                if (dy == 0 && dx == 0) center = v;
            }
        }
        float val = center + acc;
        tile[cc][tx] = val;
        if constexpr (MODE == 1) outCT[(size_t)c * NPOS + n] = val;
    }
    __syncthreads();
    for (int q = tg; q < 64; q += 4)
        outNK[(size_t)(n0 + q) * 512 + c0 + tx] = f2b(tile[tx][q]);
}

template <int MODE>
__global__ __launch_bounds__(256) void k_dw(const void* in, const hbf* w, const hbf* b,
                                            hbf* outNK, float* outCT, const void* probe) {
    __shared__ float tile[64][65];
    if constexpr (MODE == 1) {
        dw_body<1, false>(tile, in, w, b, outNK, outCT);
    } else {
        if (is_bf16_buf(probe)) dw_body<0, true>(tile, in, w, b, outNK, outCT);
        else dw_body<0, false>(tile, in, w, b, outNK, outCT);
    }
}

// ---------------------------------------------------------------------------
// Cascade window attention, MFMA version. One block (4 waves) per 7x7 window;
// 8 heads sequential (data dependence). All GEMMs on the matrix pipe:
//   QKV:  yq[96][49] = w[96][64] . spT            (A=global bf16, B=spT LDS)
//   QK^T: att[49][49] = qT[49][16] . kT[49][16]   (K padded to 32 with zeros)
//   PV:   out[64][49] = vb[64][49] . atb[49][49]  (K padded to 64 with zeros)
// Softmax fully in-register (16-lane shfl_xor reduces). PV epilogue fuses the
// hswish->ywin global write and the next head's input tile (pv + y2 slice).
// LDS ~39KB -> 4 blocks/CU (exactly one resident round of the 1024 blocks).
// ---------------------------------------------------------------------------
__global__ __launch_bounds__(256, 4) void k_attn(const float* __restrict__ y2,
                                                 const hbf* __restrict__ arena,
                                                 hbf* __restrict__ ywin) {
    __shared__ short spT[64 * 64];   // [n][c] bf16, swizzled 128B rows (B of QKV)
    __shared__ short vbT[64 * 64];   // [d][m] bf16, swizzled (A of PV); pad cols 0
    __shared__ short atb[64 * 64];   // [n][m] bf16, swizzled (B of PV); pad cols 0
    __shared__ short qT[64 * 40];    // [n][c] c<32, stride 40 (A of QK); c>=16 zero
    __shared__ short kT[64 * 40];    // [m][c] (B of QK); c>=16 zero
    __shared__ float qraw[16 * 52];  // [c][n] f32 conv staging
    __shared__ float abf[8 * 49];    // attn bias table f32

    const int tid = threadIdx.x;
    const int wave = tid >> 6, lane = tid & 63;
    const int col = lane & 15, quad = lane >> 4;
    const int w = blockIdx.x;
    const int wb = w >> 4, wh = (w >> 2) & 3, ww = w & 3;
    const size_t base = (size_t)wb * 784 + (wh * 7) * 28 + ww * 7;

    // one-time: zero MFMA pad regions (K-pads MUST be 0, and stay 0 because all
    // per-head writes are predicated to the valid <49/<16 range), stage bias.
    for (int e = tid; e < 64 * 64; e += 256) { vbT[e] = 0; atb[e] = 0; }
    for (int e = tid; e < 64 * 16; e += 256) {
        int n = e >> 4, c = 16 + (e & 15);
        qT[n * 40 + c] = 0; kT[n * 40 + c] = 0;
    }
    for (int e = tid; e < 8 * 49; e += 256) abf[e] = b2f(arena[OFF_AB + e]);

    // initial spT = spx[0] = y2 channels 0..63 of this window
    for (int e = tid; e < 64 * 49; e += 256) {
        int c = e / 49, n = e - c * 49;
        float v = y2[(size_t)c * NPOS + base + (n / 7) * 28 + (n % 7)];
        *(hbf*)((char*)spT + swz128(n, 2 * c)) = f2b(v);
    }

    // per-lane constants for C-frag epilogues (col=lane&15 -> out col n)
    int nj[4], posj[4], m7[4], mm7[4];
    bool vj[4];
#pragma unroll
    for (int j = 0; j < 4; j++) {
        nj[j] = j * 16 + col;
        vj[j] = nj[j] < 49;
        int nc = vj[j] ? nj[j] : 48;           // clamp so abf index stays in range
        m7[j] = nc / 7; mm7[j] = nc - m7[j] * 7;
        posj[j] = m7[j] * 28 + mm7[j];
    }
    const int nq = wave * 16 + quad * 4;       // C-frag out-row base for this lane

#pragma unroll 1
    for (int h = 0; h < 8; h++) {
        __syncthreads();   // spT ready; prev-head vb/atb reads complete

        // ---- QKV GEMM: wave j owns output cols n = wave*16+col ----
        const hbf* wq = arena + OFF_QKVW + h * 96 * 64;
        const int brow = wave * 16 + col;
        short8 sb0 = *(const short8*)((const char*)spT + swz128(brow, quad * 16));
        short8 sb1 = *(const short8*)((const char*)spT + swz128(brow, 64 + quad * 16));
        f32x4 yacc[6];
#pragma unroll
        for (int i = 0; i < 6; i++) {
            short8 a0 = *(const short8*)(wq + (i * 16 + col) * 64 + quad * 8);
            short8 a1 = *(const short8*)(wq + (i * 16 + col) * 64 + 32 + quad * 8);
            f32x4 z = (f32x4){0.f, 0.f, 0.f, 0.f};
            z = __builtin_amdgcn_mfma_f32_16x16x32_bf16(a0, sb0, z, 0, 0, 0);
            z = __builtin_amdgcn_mfma_f32_16x16x32_bf16(a1, sb1, z, 0, 0, 0);
            yacc[i] = z;
        }
        // route: o<16 -> qraw f32; 16..31 -> kT bf16; 32..95 -> vbT bf16
        if (brow < 49) {
            const int n = brow;
#pragma unroll
            for (int i = 0; i < 6; i++) {
                float vv[4];
#pragma unroll
                for (int r = 0; r < 4; r++)
                    vv[r] = yacc[i][r] + b2f(arena[OFF_QKVB + h * 96 + i * 16 + quad * 4 + r]);
                if (i == 0) {
#pragma unroll
                    for (int r = 0; r < 4; r++) qraw[(quad * 4 + r) * 52 + n] = vv[r];
                } else if (i == 1) {
                    *(unsigned*)((char*)kT + n * 80 + 8 * quad)     = pk2(vv[0], vv[1]);
                    *(unsigned*)((char*)kT + n * 80 + 8 * quad + 4) = pk2(vv[2], vv[3]);
                } else {
#pragma unroll
                    for (int r = 0; r < 4; r++) {
                        int d = (i - 2) * 16 + quad * 4 + r;
                        *(hbf*)((char*)vbT + swz128(d, 2 * n)) = f2b(vv[r]);
                    }
                }
            }
        }
        __syncthreads();   // qraw, kT, vbT ready

        // ---- depthwise conv on q (scalar, all 256 threads on 784 items) ----
        const hbf* cw; const hbf* cb; int ks;
        if (h == 0)      { cw = arena + OFF_W7; cb = arena + OFF_B7; ks = 7; }
        else if (h == 1) { cw = arena + OFF_W5; cb = arena + OFF_B5; ks = 5; }
        else             { cw = arena + OFF_W3 + (h - 2) * 144; cb = arena + OFF_B3 + (h - 2) * 16; ks = 3; }
        const int pad = ks >> 1;
        for (int e = tid; e < 784; e += 256) {
            int c = e / 49, n = e - c * 49;
            int r = n / 7, s = n - r * 7;
            float acc = b2f(cb[c]);
            for (int dy = 0; dy < ks; dy++) {
                int rr = r + dy - pad;
                if (rr < 0 || rr >= 7) continue;
                for (int dx = 0; dx < ks; dx++) {
                    int ss = s + dx - pad;
                    if (ss < 0 || ss >= 7) continue;
                    acc += b2f(cw[c * ks * ks + dy * ks + dx]) * qraw[c * 52 + rr * 7 + ss];
                }
            }
            // fold SCALE = 0.25 (exact) into q before bf16 quantization
            *(hbf*)((char*)qT + n * 80 + 2 * c) = f2b(acc * 0.25f);
        }
        __syncthreads();   // qT ready

        // ---- QK^T (wave i owns att rows i*16..i*16+15) + in-register softmax ----
        short8 qa = *(const short8*)((const char*)qT + (wave * 16 + col) * 80 + quad * 16);
        f32x4 sat[4];
#pragma unroll
        for (int j = 0; j < 4; j++) {
            short8 kb = *(const short8*)((const char*)kT + (j * 16 + col) * 80 + quad * 16);
            f32x4 z = (f32x4){0.f, 0.f, 0.f, 0.f};
            sat[j] = __builtin_amdgcn_mfma_f32_16x16x32_bf16(qa, kb, z, 0, 0, 0);
        }
#pragma unroll
        for (int r = 0; r < 4; r++) {
            int n = nq + r;                       // att row (>=49 rows are junk, never consumed)
            int ncl = n < 49 ? n : 48;
            int n7 = ncl / 7, nn7 = ncl - n7 * 7;
            float v0 = sat[0][r] + abf[h * 49 + abs(n7 - m7[0]) * 7 + abs(nn7 - mm7[0])];
            float v1 = sat[1][r] + abf[h * 49 + abs(n7 - m7[1]) * 7 + abs(nn7 - mm7[1])];
            float v2 = sat[2][r] + abf[h * 49 + abs(n7 - m7[2]) * 7 + abs(nn7 - mm7[2])];
            float v3 = (col == 0) ? sat[3][r] + abf[h * 49 + abs(n7 - m7[3]) * 7 + abs(nn7 - mm7[3])]
                                  : -1e30f;      // m = 48+col valid only at col==0
            float mx = fmaxf(fmaxf(v0, v1), fmaxf(v2, v3));
#pragma unroll
            for (int s = 1; s < 16; s <<= 1) mx = fmaxf(mx, __shfl_xor(mx, s));
            float p0 = __expf(v0 - mx), p1 = __expf(v1 - mx), p2 = __expf(v2 - mx);
            float p3 = (col == 0) ? __expf(v3 - mx) : 0.f;
            float sm = p0 + p1 + p2 + p3;
#pragma unroll
            for (int s = 1; s < 16; s <<= 1) sm += __shfl_xor(sm, s);
            float inv = 1.0f / sm;
            *(hbf*)((char*)atb + swz128(n, 2 * col))        = f2b(p0 * inv);
            *(hbf*)((char*)atb + swz128(n, 2 * (16 + col))) = f2b(p1 * inv);
            *(hbf*)((char*)atb + swz128(n, 2 * (32 + col))) = f2b(p2 * inv);
            if (col == 0) *(hbf*)((char*)atb + swz128(n, 2 * 48)) = f2b(p3 * inv);
        }
        __syncthreads();   // atb ready

        // ---- PV (wave i owns out rows d = wave*16..+15) + fused epilogue ----
        short8 va0 = *(const short8*)((const char*)vbT + swz128(wave * 16 + col, quad * 16));
        short8 va1 = *(const short8*)((const char*)vbT + swz128(wave * 16 + col, 64 + quad * 16));
#pragma unroll
        for (int j = 0; j < 4; j++) {
            short8 pb0 = *(const short8*)((const char*)atb + swz128(nj[j], quad * 16));
            short8 pb1 = *(const short8*)((const char*)atb + swz128(nj[j], 64 + quad * 16));
            f32x4 o = (f32x4){0.f, 0.f, 0.f, 0.f};
            o = __builtin_amdgcn_mfma_f32_16x16x32_bf16(va0, pb0, o, 0, 0, 0);
            o = __builtin_amdgcn_mfma_f32_16x16x32_bf16(va1, pb1, o, 0, 0, 0);
            if (vj[j]) {
                size_t yo = ((size_t)w * 49 + nj[j]) * 512 + h * 64 + nq;
                *(unsigned*)(ywin + yo)     = pk2(hswish(o[0]), hswish(o[1]));
                *(unsigned*)(ywin + yo + 2) = pk2(hswish(o[2]), hswish(o[3]));
                if (h < 7) {   // next head input: pv + spx[h+1]
                    const float* ys = y2 + (size_t)((h + 1) * 64 + nq) * NPOS + base + posj[j];
                    unsigned s0 = pk2(o[0] + ys[0],
                                      o[1] + ys[(size_t)NPOS]);
                    unsigned s1 = pk2(o[2] + ys[2 * (size_t)NPOS],
                                      o[3] + ys[3 * (size_t)NPOS]);
                    *(unsigned*)((char*)spT + swz128(nj[j], 2 * nq))     = s0;
                    *(unsigned*)((char*)spT + swz128(nj[j], 2 * nq + 4)) = s1;
                }
            }
        }
    }
}

// ---------------------------------------------------------------------------

extern "C" void kernel_launch(void* const* d_in, const int* in_sizes, int n_in,
                              void* d_out, int out_size, void* d_ws, size_t ws_size,
                              hipStream_t stream) {
    const void* x = d_in[0];

    if (ws_size < NEL * 10 + (size_t)ARENA_TOT * 2) return;

    uint8_t* p = (uint8_t*)d_ws;
    hbf*   R0 = (hbf*)p;                          // NEL bf16
    hbf*   R1 = (hbf*)(p + NEL * 2);              // NEL*4 bytes
    float* R2 = (float*)(p + NEL * 6);            // NEL f32
    hbf*   arena = (hbf*)(p + NEL * 10);

    hbf*   y1t  = R0;
    hbf*   hid  = R1;
    float* y2f  = R2;
    hbf*   ywin = R0;
    float* x3f  = (float*)R1;
    float* x4f  = R2;
    hbf*   x4t  = R0;
    hbf*   hid2 = R1;

    CvtTable tab = {{
        { d_in[3],  OFF_W01,  524288 },  // ffn0_w1
        { d_in[5],  OFF_W02,  524288 },  // ffn0_w2
        { d_in[20], OFF_W11,  524288 },  // ffn1_w1
        { d_in[22], OFF_W12,  524288 },  // ffn1_w2
        { d_in[16], OFF_PW,   262144 },  // proj_w
        { d_in[7],  OFF_QKVW, 49152 },   // qkv_w
        { d_in[8],  OFF_QKVB, 768 },     // qkv_b
        { d_in[9],  OFF_W7,   784 },
        { d_in[10], OFF_B7,   16 },
        { d_in[11], OFF_W5,   400 },
        { d_in[12], OFF_B5,   16 },
        { d_in[13], OFF_W3,   864 },
        { d_in[14], OFF_B3,   96 },
        { d_in[15], OFF_AB,   392 },
        { d_in[1],  OFF_D0W,  4608 },
        { d_in[2],  OFF_D0B,  512 },
        { d_in[18], OFF_D1W,  4608 },
        { d_in[19], OFF_D1B,  512 },
        { d_in[4],  OFF_B01,  1024 },
        { d_in[6],  OFF_B02,  512 },
        { d_in[21], OFF_B11,  1024 },
        { d_in[23], OFF_B12,  512 },
        { d_in[17], OFF_PB,   512 },
    }};

    dim3 blk(256);

    // 0. convert all weights/biases to bf16 arena
    k_convert<<<dim3(2048, 23), blk, 0, stream>>>(tab, arena, x);
    // 1. y1t = (x + dw0(x)) NK bf16
    k_dw<0><<<dim3(NPOS / 64, 8), blk, 0, stream>>>(x, arena + OFF_D0W, arena + OFF_D0B, y1t, nullptr, x);
    // 2. hid = hswish(y1t @ ffn0_w1^T)  NK bf16 [NPOS][1024]
    k_gemm<0, 512><<<dim3(392, 8), blk, 0, stream>>>(y1t, arena + OFF_W01, arena + OFF_B01, nullptr, hid, x);
    // 3. y2f = y1 + hid @ ffn0_w2^T  CT f32
    k_gemm<1, 1024><<<dim3(4, 392), blk, 0, stream>>>(arena + OFF_W02, hid, arena + OFF_B02, y1t, y2f, x);
    // 4. attention -> ywin NK bf16 (hswish applied)
    k_attn<<<1024, blk, 0, stream>>>(y2f, arena, ywin);
    // 5. x3f = y2 + merge(ywin @ proj_w^T)  CT f32
    k_gemm<2, 512><<<dim3(4, 392), blk, 0, stream>>>(arena + OFF_PW, ywin, arena + OFF_PB, y2f, x3f, x);
    // 6. x4f CT f32 + x4t NK bf16 = x3 + dw1(x3)
    k_dw<1><<<dim3(NPOS / 64, 8), blk, 0, stream>>>(x3f, arena + OFF_D1W, arena + OFF_D1B, x4t, x4f, x);
    // 7. hid2 = hswish(x4t @ ffn1_w1^T)
    k_gemm<0, 512><<<dim3(392, 8), blk, 0, stream>>>(x4t, arena + OFF_W11, arena + OFF_B11, nullptr, hid2, x);
    // 8. out = x4 + hid2 @ ffn1_w2^T  NCHW (dtype per probe)
    k_gemm<3, 1024><<<dim3(4, 392), blk, 0, stream>>>(arena + OFF_W12, hid2, arena + OFF_B12, x4f, d_out, x);
}

// Round 3
// 1142.570 us; speedup vs baseline: 1.6898x; 1.2413x over previous
//
#include <hip/hip_runtime.h>
#include <hip/hip_bf16.h>

// ---------------------------------------------------------------------------
// BasicBlock (EfficientViT-style) on MI355X. Input dtype (fp32 vs bf16) is
// runtime-detected; all weights are pre-converted into a bf16 arena in ws so
// the compute kernels are dtype-free. GEMMs: bf16 MFMA, fp32 accum.
//
// Layouts:
//   CT = [C][N]  n-contiguous (N = 50176 = 64*784) fp32, residuals/attn in.
//   NK = [N][K]  k-contiguous bf16, MFMA GEMM operands (ds_read_b128 frags).
// ---------------------------------------------------------------------------

#define NPOS 50176                  // 64 * 784
#define NEL ((size_t)512 * NPOS)

typedef __hip_bfloat16 hbf;
typedef __attribute__((ext_vector_type(8))) short short8;   // 8 bf16
typedef __attribute__((ext_vector_type(4))) short bf16x4;   // 4 bf16
typedef __attribute__((ext_vector_type(4))) float f32x4;

__device__ __forceinline__ float hswish(float v) {
    float t = fminf(fmaxf(v + 3.0f, 0.0f), 6.0f);
    return v * t * (1.0f / 6.0f);
}
__device__ __forceinline__ float b2f(hbf x) { return __bfloat162float(x); }
__device__ __forceinline__ hbf f2b(float x) { return __float2bfloat16(x); }

__device__ __forceinline__ unsigned short bfb(float v) {
    hbf h = f2b(v); unsigned short u; __builtin_memcpy(&u, &h, 2); return u;
}
__device__ __forceinline__ unsigned pk2(float a, float b) {
    return (unsigned)bfb(a) | ((unsigned)bfb(b) << 16);
}
// byte address into a [row][64 bf16] (=128B rows) LDS array, XOR-swizzled so
// that column-slice ds_read_b128 across 16 lanes is ~2-way conflict free.
__device__ __forceinline__ int swz128(int row, int b) {
    return row * 128 + (b ^ ((row & 7) << 4));
}

// Probe x's dtype: low 16 bits of fp32 words are random mantissa bits (~16%
// "sane bf16 exponent" rate); in a packed-bf16 buffer they are real bf16
// values (~100%). 64 words, threshold 32 -> error prob < 1e-10.
__device__ __forceinline__ bool is_bf16_buf(const void* probe) {
    const unsigned* w = (const unsigned*)probe;
    int hits = 0;
#pragma unroll
    for (int i = 0; i < 64; i++) {
        unsigned lo = w[i] & 0xFFFFu;
        unsigned e = (lo >> 7) & 0xFFu;
        hits += ((e >= 100u && e <= 140u) || lo == 0u) ? 1 : 0;
    }
    return hits >= 32;
}

// ---------------------------------------------------------------------------
// Weight arena (bf16) — compile-time element offsets.
// ---------------------------------------------------------------------------
#define OFF_W01  0          // ffn0_w1 [1024][512]
#define OFF_W02  524288     // ffn0_w2 [512][1024]
#define OFF_W11  1048576    // ffn1_w1 [1024][512]
#define OFF_W12  1572864    // ffn1_w2 [512][1024]
#define OFF_PW   2097152    // proj_w  [512][512]
#define OFF_QKVW 2359296    // qkv_w   [8][96][64]
#define OFF_QKVB 2408448    // qkv_b   [8][96]
#define OFF_W7   2409216
#define OFF_B7   2410000
#define OFF_W5   2410016
#define OFF_B5   2410416
#define OFF_W3   2410432    // [6][16][9]
#define OFF_B3   2411296    // [6][16]
#define OFF_AB   2411392    // [8][49]
#define OFF_D0W  2411784    // dw0_w [512][9]
#define OFF_D0B  2416392
#define OFF_D1W  2416904
#define OFF_D1B  2421512
#define OFF_B01  2422024    // ffn0_b1 [1024]
#define OFF_B02  2423048
#define OFF_B11  2423560
#define OFF_B12  2424584
#define OFF_PB   2425096
#define ARENA_TOT 2425608

struct CvtArgs { const void* src; int off; int count; };
struct CvtTable { CvtArgs t[23]; };

__global__ __launch_bounds__(256) void k_convert(CvtTable tab, hbf* __restrict__ arena,
                                                 const void* __restrict__ probe) {
    CvtArgs a = tab.t[blockIdx.y];
    int i = blockIdx.x * 256 + threadIdx.x;
    if (i >= a.count) return;            // bounds-check BEFORE the 64-load probe
    bool isbf = is_bf16_buf(probe);
    float v = isbf ? b2f(((const hbf*)a.src)[i]) : ((const float*)a.src)[i];
    arena[a.off + i] = f2b(v);
}

// ---------------------------------------------------------------------------
// MFMA GEMM: D[m][n] = A[m][:] . B[n][:]  (both k-contiguous rows, bf16)
// 128x128 tile, BK=32, 4 waves, 4x4 frags of mfma_f32_16x16x32_bf16.
// EPI: 0=HID  bf16 NK [m_sp][1024] = hswish(acc + bias[n])
//      1=Y2   f32 CT [m_och][NPOS] = acc + bias[m] + bf16resNK[n][512]
//      2=PROJ f32 CT [m_och][perm(n)] = acc + bias[m] + f32resCT[same]
//      3=OUT  NCHW (bf16 or f32 per probe) = acc + bias[m] + f32resCT
// ---------------------------------------------------------------------------
template <int EPI, int K>
__global__ __launch_bounds__(256) void k_gemm(const hbf* __restrict__ A,
                                              const hbf* __restrict__ B,
                                              const hbf* __restrict__ bias,
                                              const void* __restrict__ res,
                                              void* __restrict__ out,
                                              const void* __restrict__ probe) {
    __shared__ short sA[128 * 40];   // 32 k padded to 40 shorts (80 B rows)
    __shared__ short sB[128 * 40];

    const int tid = threadIdx.x;
    const int wave = tid >> 6, lane = tid & 63;
    const int col = lane & 15, quad = lane >> 4;
    const int m0 = blockIdx.x * 128, n0 = blockIdx.y * 128;
    const int wm = (wave & 1) * 64, wn = (wave >> 1) * 64;

    const int r0 = tid >> 2, c0 = tid & 3;
    const int r1 = 64 + (tid >> 2), c1 = tid & 3;

    f32x4 acc[4][4];
#pragma unroll
    for (int i = 0; i < 4; i++)
#pragma unroll
        for (int j = 0; j < 4; j++) acc[i][j] = (f32x4){0.f, 0.f, 0.f, 0.f};

    short8 pA0 = *(const short8*)(A + (size_t)(m0 + r0) * K + c0 * 8);
    short8 pA1 = *(const short8*)(A + (size_t)(m0 + r1) * K + c1 * 8);
    short8 pB0 = *(const short8*)(B + (size_t)(n0 + r0) * K + c0 * 8);
    short8 pB1 = *(const short8*)(B + (size_t)(n0 + r1) * K + c1 * 8);

    for (int k0 = 0; k0 < K; k0 += 32) {
        __syncthreads();
        *(short8*)(sA + r0 * 40 + c0 * 8) = pA0;
        *(short8*)(sA + r1 * 40 + c1 * 8) = pA1;
        *(short8*)(sB + r0 * 40 + c0 * 8) = pB0;
        *(short8*)(sB + r1 * 40 + c1 * 8) = pB1;
        if (k0 + 32 < K) {
            pA0 = *(const short8*)(A + (size_t)(m0 + r0) * K + k0 + 32 + c0 * 8);
            pA1 = *(const short8*)(A + (size_t)(m0 + r1) * K + k0 + 32 + c1 * 8);
            pB0 = *(const short8*)(B + (size_t)(n0 + r0) * K + k0 + 32 + c0 * 8);
            pB1 = *(const short8*)(B + (size_t)(n0 + r1) * K + k0 + 32 + c1 * 8);
        }
        __syncthreads();

        short8 af[4], bfr[4];
#pragma unroll
        for (int i = 0; i < 4; i++)
            af[i] = *(const short8*)(sA + (wm + i * 16 + col) * 40 + quad * 8);
#pragma unroll
        for (int j = 0; j < 4; j++)
            bfr[j] = *(const short8*)(sB + (wn + j * 16 + col) * 40 + quad * 8);
#pragma unroll
        for (int i = 0; i < 4; i++)
#pragma unroll
            for (int j = 0; j < 4; j++)
                acc[i][j] = __builtin_amdgcn_mfma_f32_16x16x32_bf16(af[i], bfr[j], acc[i][j], 0, 0, 0);
    }

    bool outbf = false;
    if constexpr (EPI == 3) outbf = is_bf16_buf(probe);

#pragma unroll
    for (int i = 0; i < 4; i++) {
#pragma unroll
        for (int j = 0; j < 4; j++) {
#pragma unroll
            for (int r = 0; r < 4; r++) {
                int mi = m0 + wm + i * 16 + quad * 4 + r;
                int nj = n0 + wn + j * 16 + col;
                float v = acc[i][j][r];
                if constexpr (EPI == 0) {
                    v = hswish(v + b2f(bias[nj]));
                    ((hbf*)out)[(size_t)mi * 1024 + nj] = f2b(v);
                } else if constexpr (EPI == 1) {
                    v += b2f(bias[mi]) + b2f(((const hbf*)res)[(size_t)nj * 512 + mi]);
                    ((float*)out)[(size_t)mi * NPOS + nj] = v;
                } else if constexpr (EPI == 2) {
                    int w = nj / 49, p = nj % 49;
                    int nct = (w >> 4) * 784 + (((w >> 2) & 3) * 7 + p / 7) * 28 + (w & 3) * 7 + p % 7;
                    size_t oi = (size_t)mi * NPOS + nct;
                    v += b2f(bias[mi]) + ((const float*)res)[oi];
                    ((float*)out)[oi] = v;
                } else {
                    int b = nj / 784, hw = nj % 784;
                    v += b2f(bias[mi]) + ((const float*)res)[(size_t)mi * NPOS + nj];
                    size_t oi = ((size_t)b * 512 + mi) * 784 + hw;
                    if (outbf) ((hbf*)out)[oi] = f2b(v);
                    else ((float*)out)[oi] = v;
                }
            }
        }
    }
}

// ---------------------------------------------------------------------------
// Depthwise 3x3 + residual, LDS-staged (latency fix: the old version issued 9
// divergent scalar global loads per output in a serial FMA chain -> ~700 GB/s.
// Now: coalesced float4 staging of [64ch][128pos] into LDS, branch-free
// stencil from LDS, register-held results, transpose tile aliases the stage.)
// MODE 0: in = x NCHW (dtype per probe)  -> outNK
// MODE 1: in = x3f CT f32 -> outNK + outCT f32
// Positions staged: n0-32 .. n0+95. A float4 never straddles a batch boundary
// (784 % 4 == 0); clamped staging addresses are safe because the r/s masks
// guarantee out-of-image slots are never consumed.
// ---------------------------------------------------------------------------
template <int MODE, bool ISBF>
__device__ void dw_body(float* sIn, float* sW, const void* __restrict__ in,
                        const hbf* __restrict__ w, const hbf* __restrict__ bias,
                        hbf* __restrict__ outNK, float* __restrict__ outCT) {
    const int tid = threadIdx.x;
    const int tx = tid & 63, tg = tid >> 6;
    const int n0 = blockIdx.x * 64, c0 = blockIdx.y * 64;

    // ---- stage weights + bias: sW[cc*10 + t], t=9 is bias ----
    for (int e = tid; e < 640; e += 256) {
        int cc = e / 10, t = e - cc * 10;
        sW[e] = (t < 9) ? b2f(w[(c0 + cc) * 9 + t]) : b2f(bias[c0 + cc]);
    }

    // ---- stage input window sIn[64][128] f32 (8 x float4 per thread) ----
#pragma unroll
    for (int k = 0; k < 8; k++) {
        int idx = tid + k * 256;          // 2048 float4 slots
        int ch = idx >> 5, j4 = idx & 31;
        int p = n0 - 32 + j4 * 4;
        p = p < 0 ? 0 : (p > NPOS - 4 ? NPOS - 4 : p);
        f32x4 v;
        if constexpr (MODE == 1) {
            v = *(const f32x4*)((const float*)in + (size_t)(c0 + ch) * NPOS + p);
        } else {
            int b = p / 784, hw = p - b * 784;
            size_t ix = ((size_t)b * 512 + c0 + ch) * 784 + hw;
            if constexpr (ISBF) {
                bf16x4 t4 = *(const bf16x4*)((const hbf*)in + ix);
#pragma unroll
                for (int j = 0; j < 4; j++) {
                    unsigned u = (unsigned)(unsigned short)t4[j] << 16;
                    v[j] = __uint_as_float(u);
                }
            } else {
                v = *(const f32x4*)((const float*)in + ix);
            }
        }
        *(f32x4*)(sIn + ch * 128 + j4 * 4) = v;
    }
    __syncthreads();

    // ---- branch-free 3x3 stencil from LDS ----
    const int n = n0 + tx;
    const int b = n / 784, hw = n - b * 784;
    const int r = hw / 28, s = hw - r * 28;
    const float mrow[3] = { r > 0 ? 1.f : 0.f, 1.f, r < 27 ? 1.f : 0.f };
    const float mcol[3] = { s > 0 ? 1.f : 0.f, 1.f, s < 27 ? 1.f : 0.f };

    float vals[16];
#pragma unroll
    for (int i = 0; i < 16; i++) {
        const int cc = tg + 4 * i;
        const float* row = sIn + cc * 128 + 32 + tx;
        float acc = sW[cc * 10 + 9];
        float center = row[0];
#pragma unroll
        for (int dy = 0; dy < 3; dy++)
#pragma unroll
            for (int dx = 0; dx < 3; dx++)
                acc = fmaf(row[(dy - 1) * 28 + (dx - 1)],
                           mrow[dy] * mcol[dx] * sW[cc * 10 + dy * 3 + dx], acc);
        float val = center + acc;
        vals[i] = val;
        if constexpr (MODE == 1) outCT[(size_t)(c0 + cc) * NPOS + n] = val;
    }
    __syncthreads();

    // ---- transpose via LDS (aliases sIn) and write NK bf16 ----
    float (*tile)[65] = (float (*)[65])sIn;
#pragma unroll
    for (int i = 0; i < 16; i++) tile[tg + 4 * i][tx] = vals[i];
    __syncthreads();
    for (int q = tg; q < 64; q += 4)
        outNK[(size_t)(n0 + q) * 512 + c0 + tx] = f2b(tile[tx][q]);
}

template <int MODE>
__global__ __launch_bounds__(256, 4) void k_dw(const void* in, const hbf* w, const hbf* b,
                                               hbf* outNK, float* outCT, const void* probe) {
    __shared__ float sIn[64 * 128];   // 32 KB stage; transpose tile aliases it
    __shared__ float sW[64 * 10];
    if constexpr (MODE == 1) {
        dw_body<1, false>(sIn, sW, in, w, b, outNK, outCT);
    } else {
        if (is_bf16_buf(probe)) dw_body<0, true>(sIn, sW, in, w, b, outNK, outCT);
        else dw_body<0, false>(sIn, sW, in, w, b, outNK, outCT);
    }
}

// ---------------------------------------------------------------------------
// Cascade window attention, MFMA version. One block (4 waves) per 7x7 window;
// 8 heads sequential (data dependence). All GEMMs on the matrix pipe:
//   QKV:  yq[96][49] = w[96][64] . spT            (A=global bf16, B=spT LDS)
//   QK^T: att[49][49] = qT[49][16] . kT[49][16]   (K padded to 32 with zeros)
//   PV:   out[64][49] = vb[64][49] . atb[49][49]  (K padded to 64 with zeros)
// Softmax fully in-register (16-lane shfl_xor reduces). PV epilogue fuses the
// hswish->ywin global write and the next head's input tile (pv + y2 slice).
// ---------------------------------------------------------------------------
__global__ __launch_bounds__(256, 4) void k_attn(const float* __restrict__ y2,
                                                 const hbf* __restrict__ arena,
                                                 hbf* __restrict__ ywin) {
    __shared__ short spT[64 * 64];   // [n][c] bf16, swizzled 128B rows (B of QKV)
    __shared__ short vbT[64 * 64];   // [d][m] bf16, swizzled (A of PV); pad cols 0
    __shared__ short atb[64 * 64];   // [n][m] bf16, swizzled (B of PV); pad cols 0
    __shared__ short qT[64 * 40];    // [n][c] c<32, stride 40 (A of QK); c>=16 zero
    __shared__ short kT[64 * 40];    // [m][c] (B of QK); c>=16 zero
    __shared__ float qraw[16 * 52];  // [c][n] f32 conv staging
    __shared__ float abf[8 * 49];    // attn bias table f32

    const int tid = threadIdx.x;
    const int wave = tid >> 6, lane = tid & 63;
    const int col = lane & 15, quad = lane >> 4;
    const int w = blockIdx.x;
    const int wb = w >> 4, wh = (w >> 2) & 3, ww = w & 3;
    const size_t base = (size_t)wb * 784 + (wh * 7) * 28 + ww * 7;

    // one-time: zero MFMA pad regions (K-pads MUST be 0, and stay 0 because all
    // per-head writes are predicated to the valid <49/<16 range), stage bias.
    for (int e = tid; e < 64 * 64; e += 256) { vbT[e] = 0; atb[e] = 0; }
    for (int e = tid; e < 64 * 16; e += 256) {
        int n = e >> 4, c = 16 + (e & 15);
        qT[n * 40 + c] = 0; kT[n * 40 + c] = 0;
    }
    for (int e = tid; e < 8 * 49; e += 256) abf[e] = b2f(arena[OFF_AB + e]);

    // initial spT = spx[0] = y2 channels 0..63 of this window
    for (int e = tid; e < 64 * 49; e += 256) {
        int c = e / 49, n = e - c * 49;
        float v = y2[(size_t)c * NPOS + base + (n / 7) * 28 + (n % 7)];
        *(hbf*)((char*)spT + swz128(n, 2 * c)) = f2b(v);
    }

    // per-lane constants for C-frag epilogues (col=lane&15 -> out col n)
    int nj[4], posj[4], m7[4], mm7[4];
    bool vj[4];
#pragma unroll
    for (int j = 0; j < 4; j++) {
        nj[j] = j * 16 + col;
        vj[j] = nj[j] < 49;
        int nc = vj[j] ? nj[j] : 48;           // clamp so abf index stays in range
        m7[j] = nc / 7; mm7[j] = nc - m7[j] * 7;
        posj[j] = m7[j] * 28 + mm7[j];
    }
    const int nq = wave * 16 + quad * 4;       // C-frag out-row base for this lane

#pragma unroll 1
    for (int h = 0; h < 8; h++) {
        __syncthreads();   // spT ready; prev-head vb/atb reads complete

        // ---- QKV GEMM: wave j owns output cols n = wave*16+col ----
        const hbf* wq = arena + OFF_QKVW + h * 96 * 64;
        const int brow = wave * 16 + col;
        short8 sb0 = *(const short8*)((const char*)spT + swz128(brow, quad * 16));
        short8 sb1 = *(const short8*)((const char*)spT + swz128(brow, 64 + quad * 16));
        f32x4 yacc[6];
#pragma unroll
        for (int i = 0; i < 6; i++) {
            short8 a0 = *(const short8*)(wq + (i * 16 + col) * 64 + quad * 8);
            short8 a1 = *(const short8*)(wq + (i * 16 + col) * 64 + 32 + quad * 8);
            f32x4 z = (f32x4){0.f, 0.f, 0.f, 0.f};
            z = __builtin_amdgcn_mfma_f32_16x16x32_bf16(a0, sb0, z, 0, 0, 0);
            z = __builtin_amdgcn_mfma_f32_16x16x32_bf16(a1, sb1, z, 0, 0, 0);
            yacc[i] = z;
        }
        // route: o<16 -> qraw f32; 16..31 -> kT bf16; 32..95 -> vbT bf16
        if (brow < 49) {
            const int n = brow;
#pragma unroll
            for (int i = 0; i < 6; i++) {
                float vv[4];
#pragma unroll
                for (int r = 0; r < 4; r++)
                    vv[r] = yacc[i][r] + b2f(arena[OFF_QKVB + h * 96 + i * 16 + quad * 4 + r]);
                if (i == 0) {
#pragma unroll
                    for (int r = 0; r < 4; r++) qraw[(quad * 4 + r) * 52 + n] = vv[r];
                } else if (i == 1) {
                    *(unsigned*)((char*)kT + n * 80 + 8 * quad)     = pk2(vv[0], vv[1]);
                    *(unsigned*)((char*)kT + n * 80 + 8 * quad + 4) = pk2(vv[2], vv[3]);
                } else {
#pragma unroll
                    for (int r = 0; r < 4; r++) {
                        int d = (i - 2) * 16 + quad * 4 + r;
                        *(hbf*)((char*)vbT + swz128(d, 2 * n)) = f2b(vv[r]);
                    }
                }
            }
        }
        __syncthreads();   // qraw, kT, vbT ready

        // ---- depthwise conv on q (scalar, all 256 threads on 784 items) ----
        const hbf* cw; const hbf* cb; int ks;
        if (h == 0)      { cw = arena + OFF_W7; cb = arena + OFF_B7; ks = 7; }
        else if (h == 1) { cw = arena + OFF_W5; cb = arena + OFF_B5; ks = 5; }
        else             { cw = arena + OFF_W3 + (h - 2) * 144; cb = arena + OFF_B3 + (h - 2) * 16; ks = 3; }
        const int pad = ks >> 1;
        for (int e = tid; e < 784; e += 256) {
            int c = e / 49, n = e - c * 49;
            int r = n / 7, s = n - r * 7;
            float acc = b2f(cb[c]);
            for (int dy = 0; dy < ks; dy++) {
                int rr = r + dy - pad;
                if (rr < 0 || rr >= 7) continue;
                for (int dx = 0; dx < ks; dx++) {
                    int ss = s + dx - pad;
                    if (ss < 0 || ss >= 7) continue;
                    acc += b2f(cw[c * ks * ks + dy * ks + dx]) * qraw[c * 52 + rr * 7 + ss];
                }
            }
            // fold SCALE = 0.25 (exact) into q before bf16 quantization
            *(hbf*)((char*)qT + n * 80 + 2 * c) = f2b(acc * 0.25f);
        }
        __syncthreads();   // qT ready

        // ---- QK^T (wave i owns att rows i*16..i*16+15) + in-register softmax ----
        short8 qa = *(const short8*)((const char*)qT + (wave * 16 + col) * 80 + quad * 16);
        f32x4 sat[4];
#pragma unroll
        for (int j = 0; j < 4; j++) {
            short8 kb = *(const short8*)((const char*)kT + (j * 16 + col) * 80 + quad * 16);
            f32x4 z = (f32x4){0.f, 0.f, 0.f, 0.f};
            sat[j] = __builtin_amdgcn_mfma_f32_16x16x32_bf16(qa, kb, z, 0, 0, 0);
        }
#pragma unroll
        for (int r = 0; r < 4; r++) {
            int n = nq + r;                       // att row (>=49 rows are junk, never consumed)
            int ncl = n < 49 ? n : 48;
            int n7 = ncl / 7, nn7 = ncl - n7 * 7;
            float v0 = sat[0][r] + abf[h * 49 + abs(n7 - m7[0]) * 7 + abs(nn7 - mm7[0])];
            float v1 = sat[1][r] + abf[h * 49 + abs(n7 - m7[1]) * 7 + abs(nn7 - mm7[1])];
            float v2 = sat[2][r] + abf[h * 49 + abs(n7 - m7[2]) * 7 + abs(nn7 - mm7[2])];
            float v3 = (col == 0) ? sat[3][r] + abf[h * 49 + abs(n7 - m7[3]) * 7 + abs(nn7 - mm7[3])]
                                  : -1e30f;      // m = 48+col valid only at col==0
            float mx = fmaxf(fmaxf(v0, v1), fmaxf(v2, v3));
#pragma unroll
            for (int s = 1; s < 16; s <<= 1) mx = fmaxf(mx, __shfl_xor(mx, s));
            float p0 = __expf(v0 - mx), p1 = __expf(v1 - mx), p2 = __expf(v2 - mx);
            float p3 = (col == 0) ? __expf(v3 - mx) : 0.f;
            float sm = p0 + p1 + p2 + p3;
#pragma unroll
            for (int s = 1; s < 16; s <<= 1) sm += __shfl_xor(sm, s);
            float inv = 1.0f / sm;
            *(hbf*)((char*)atb + swz128(n, 2 * col))        = f2b(p0 * inv);
            *(hbf*)((char*)atb + swz128(n, 2 * (16 + col))) = f2b(p1 * inv);
            *(hbf*)((char*)atb + swz128(n, 2 * (32 + col))) = f2b(p2 * inv);
            if (col == 0) *(hbf*)((char*)atb + swz128(n, 2 * 48)) = f2b(p3 * inv);
        }
        __syncthreads();   // atb ready

        // ---- PV (wave i owns out rows d = wave*16..+15) + fused epilogue ----
        short8 va0 = *(const short8*)((const char*)vbT + swz128(wave * 16 + col, quad * 16));
        short8 va1 = *(const short8*)((const char*)vbT + swz128(wave * 16 + col, 64 + quad * 16));
#pragma unroll
        for (int j = 0; j < 4; j++) {
            short8 pb0 = *(const short8*)((const char*)atb + swz128(nj[j], quad * 16));
            short8 pb1 = *(const short8*)((const char*)atb + swz128(nj[j], 64 + quad * 16));
            f32x4 o = (f32x4){0.f, 0.f, 0.f, 0.f};
            o = __builtin_amdgcn_mfma_f32_16x16x32_bf16(va0, pb0, o, 0, 0, 0);
            o = __builtin_amdgcn_mfma_f32_16x16x32_bf16(va1, pb1, o, 0, 0, 0);
            if (vj[j]) {
                size_t yo = ((size_t)w * 49 + nj[j]) * 512 + h * 64 + nq;
                *(unsigned*)(ywin + yo)     = pk2(hswish(o[0]), hswish(o[1]));
                *(unsigned*)(ywin + yo + 2) = pk2(hswish(o[2]), hswish(o[3]));
                if (h < 7) {   // next head input: pv + spx[h+1]
                    const float* ys = y2 + (size_t)((h + 1) * 64 + nq) * NPOS + base + posj[j];
                    unsigned s0 = pk2(o[0] + ys[0],
                                      o[1] + ys[(size_t)NPOS]);
                    unsigned s1 = pk2(o[2] + ys[2 * (size_t)NPOS],
                                      o[3] + ys[3 * (size_t)NPOS]);
                    *(unsigned*)((char*)spT + swz128(nj[j], 2 * nq))     = s0;
                    *(unsigned*)((char*)spT + swz128(nj[j], 2 * nq + 4)) = s1;
                }
            }
        }
    }
}

// ---------------------------------------------------------------------------

extern "C" void kernel_launch(void* const* d_in, const int* in_sizes, int n_in,
                              void* d_out, int out_size, void* d_ws, size_t ws_size,
                              hipStream_t stream) {
    const void* x = d_in[0];

    if (ws_size < NEL * 10 + (size_t)ARENA_TOT * 2) return;

    uint8_t* p = (uint8_t*)d_ws;
    hbf*   R0 = (hbf*)p;                          // NEL bf16
    hbf*   R1 = (hbf*)(p + NEL * 2);              // NEL*4 bytes
    float* R2 = (float*)(p + NEL * 6);            // NEL f32
    hbf*   arena = (hbf*)(p + NEL * 10);

    hbf*   y1t  = R0;
    hbf*   hid  = R1;
    float* y2f  = R2;
    hbf*   ywin = R0;
    float* x3f  = (float*)R1;
    float* x4f  = R2;
    hbf*   x4t  = R0;
    hbf*   hid2 = R1;

    CvtTable tab = {{
        { d_in[3],  OFF_W01,  524288 },  // ffn0_w1
        { d_in[5],  OFF_W02,  524288 },  // ffn0_w2
        { d_in[20], OFF_W11,  524288 },  // ffn1_w1
        { d_in[22], OFF_W12,  524288 },  // ffn1_w2
        { d_in[16], OFF_PW,   262144 },  // proj_w
        { d_in[7],  OFF_QKVW, 49152 },   // qkv_w
        { d_in[8],  OFF_QKVB, 768 },     // qkv_b
        { d_in[9],  OFF_W7,   784 },
        { d_in[10], OFF_B7,   16 },
        { d_in[11], OFF_W5,   400 },
        { d_in[12], OFF_B5,   16 },
        { d_in[13], OFF_W3,   864 },
        { d_in[14], OFF_B3,   96 },
        { d_in[15], OFF_AB,   392 },
        { d_in[1],  OFF_D0W,  4608 },
        { d_in[2],  OFF_D0B,  512 },
        { d_in[18], OFF_D1W,  4608 },
        { d_in[19], OFF_D1B,  512 },
        { d_in[4],  OFF_B01,  1024 },
        { d_in[6],  OFF_B02,  512 },
        { d_in[21], OFF_B11,  1024 },
        { d_in[23], OFF_B12,  512 },
        { d_in[17], OFF_PB,   512 },
    }};

    dim3 blk(256);

    // 0. convert all weights/biases to bf16 arena
    k_convert<<<dim3(2048, 23), blk, 0, stream>>>(tab, arena, x);
    // 1. y1t = (x + dw0(x)) NK bf16
    k_dw<0><<<dim3(NPOS / 64, 8), blk, 0, stream>>>(x, arena + OFF_D0W, arena + OFF_D0B, y1t, nullptr, x);
    // 2. hid = hswish(y1t @ ffn0_w1^T)  NK bf16 [NPOS][1024]
    k_gemm<0, 512><<<dim3(392, 8), blk, 0, stream>>>(y1t, arena + OFF_W01, arena + OFF_B01, nullptr, hid, x);
    // 3. y2f = y1 + hid @ ffn0_w2^T  CT f32
    k_gemm<1, 1024><<<dim3(4, 392), blk, 0, stream>>>(arena + OFF_W02, hid, arena + OFF_B02, y1t, y2f, x);
    // 4. attention -> ywin NK bf16 (hswish applied)
    k_attn<<<1024, blk, 0, stream>>>(y2f, arena, ywin);
    // 5. x3f = y2 + merge(ywin @ proj_w^T)  CT f32
    k_gemm<2, 512><<<dim3(4, 392), blk, 0, stream>>>(arena + OFF_PW, ywin, arena + OFF_PB, y2f, x3f, x);
    // 6. x4f CT f32 + x4t NK bf16 = x3 + dw1(x3)
    k_dw<1><<<dim3(NPOS / 64, 8), blk, 0, stream>>>(x3f, arena + OFF_D1W, arena + OFF_D1B, x4t, x4f, x);
    // 7. hid2 = hswish(x4t @ ffn1_w1^T)
    k_gemm<0, 512><<<dim3(392, 8), blk, 0, stream>>>(x4t, arena + OFF_W11, arena + OFF_B11, nullptr, hid2, x);
    // 8. out = x4 + hid2 @ ffn1_w2^T  NCHW (dtype per probe)
    k_gemm<3, 1024><<<dim3(4, 392), blk, 0, stream>>>(arena + OFF_W12, hid2, arena + OFF_B12, x4f, d_out, x);
}

// Round 4
// 1139.449 us; speedup vs baseline: 1.6944x; 1.0027x over previous
//
#include <hip/hip_runtime.h>
#include <hip/hip_bf16.h>

// ---------------------------------------------------------------------------
// BasicBlock (EfficientViT-style) on MI355X. Input dtype (fp32 vs bf16) is
// runtime-detected; all weights are pre-converted into a bf16 arena in ws so
// the compute kernels are dtype-free. GEMMs: bf16 MFMA, fp32 accum.
//
// Layouts:
//   CT = [C][N]  n-contiguous (N = 50176 = 64*784) fp32, residuals/attn in.
//   NK = [N][K]  k-contiguous bf16, MFMA GEMM operands (ds_read_b128 frags).
// ---------------------------------------------------------------------------

#define NPOS 50176                  // 64 * 784
#define NEL ((size_t)512 * NPOS)

typedef __hip_bfloat16 hbf;
typedef unsigned int u32;
typedef __attribute__((ext_vector_type(8))) short short8;   // 8 bf16
typedef __attribute__((ext_vector_type(4))) short bf16x4;   // 4 bf16
typedef __attribute__((ext_vector_type(4))) float f32x4;

__device__ __forceinline__ float hswish(float v) {
    float t = fminf(fmaxf(v + 3.0f, 0.0f), 6.0f);
    return v * t * (1.0f / 6.0f);
}
__device__ __forceinline__ float b2f(hbf x) { return __bfloat162float(x); }
__device__ __forceinline__ hbf f2b(float x) { return __float2bfloat16(x); }

__device__ __forceinline__ unsigned short bfb(float v) {
    hbf h = f2b(v); unsigned short u; __builtin_memcpy(&u, &h, 2); return u;
}
__device__ __forceinline__ unsigned pk2(float a, float b) {
    return (unsigned)bfb(a) | ((unsigned)bfb(b) << 16);
}
// byte address into a [row][64 bf16] (=128B rows) LDS array, XOR-swizzled so
// that column-slice ds_read_b128 across 16 lanes is ~2-way conflict free.
__device__ __forceinline__ int swz128(int row, int b) {
    return row * 128 + (b ^ ((row & 7) << 4));
}
// async global->LDS, 16B per lane. LDS dest = uniform base + lane*16.
__device__ __forceinline__ void gl16(const hbf* g, short* l) {
    __builtin_amdgcn_global_load_lds((const __attribute__((address_space(1))) u32*)g,
                                     (__attribute__((address_space(3))) u32*)l,
                                     16, 0, 0);
}

// Probe x's dtype: low 16 bits of fp32 words are random mantissa bits (~16%
// "sane bf16 exponent" rate); in a packed-bf16 buffer they are real bf16
// values (~100%). 64 words, threshold 32 -> error prob < 1e-10.
__device__ __forceinline__ bool is_bf16_buf(const void* probe) {
    const unsigned* w = (const unsigned*)probe;
    int hits = 0;
#pragma unroll
    for (int i = 0; i < 64; i++) {
        unsigned lo = w[i] & 0xFFFFu;
        unsigned e = (lo >> 7) & 0xFFu;
        hits += ((e >= 100u && e <= 140u) || lo == 0u) ? 1 : 0;
    }
    return hits >= 32;
}

// ---------------------------------------------------------------------------
// Weight arena (bf16) — compile-time element offsets.
// ---------------------------------------------------------------------------
#define OFF_W01  0          // ffn0_w1 [1024][512]
#define OFF_W02  524288     // ffn0_w2 [512][1024]
#define OFF_W11  1048576    // ffn1_w1 [1024][512]
#define OFF_W12  1572864    // ffn1_w2 [512][1024]
#define OFF_PW   2097152    // proj_w  [512][512]
#define OFF_QKVW 2359296    // qkv_w   [8][96][64]
#define OFF_QKVB 2408448    // qkv_b   [8][96]
#define OFF_W7   2409216
#define OFF_B7   2410000
#define OFF_W5   2410016
#define OFF_B5   2410416
#define OFF_W3   2410432    // [6][16][9]
#define OFF_B3   2411296    // [6][16]
#define OFF_AB   2411392    // [8][49]
#define OFF_D0W  2411784    // dw0_w [512][9]
#define OFF_D0B  2416392
#define OFF_D1W  2416904
#define OFF_D1B  2421512
#define OFF_B01  2422024    // ffn0_b1 [1024]
#define OFF_B02  2423048
#define OFF_B11  2423560
#define OFF_B12  2424584
#define OFF_PB   2425096
#define ARENA_TOT 2425608

struct CvtArgs { const void* src; int off; int count; };
struct CvtTable { CvtArgs t[23]; };

__global__ __launch_bounds__(256) void k_convert(CvtTable tab, hbf* __restrict__ arena,
                                                 const void* __restrict__ probe) {
    CvtArgs a = tab.t[blockIdx.y];
    int i = blockIdx.x * 256 + threadIdx.x;
    if (i >= a.count) return;            // bounds-check BEFORE the 64-load probe
    bool isbf = is_bf16_buf(probe);
    float v = isbf ? b2f(((const hbf*)a.src)[i]) : ((const float*)a.src)[i];
    arena[a.off + i] = f2b(v);
}

// ---------------------------------------------------------------------------
// MFMA GEMM: D[m][n] = A[m][:] . B[n][:]  (both k-contiguous rows, bf16)
// m97 structure: 128x128 tile, BK=64, 4 waves, 4x4 frags, 16x16x32 MFMA.
// Staging is pure global_load_lds (dwordx4): LDS [128 rows][8 x 16B slots]
// linear; bank-conflict fix per Rule 21 = pre-swizzled GLOBAL source
// (slot_logical = (lane&7) ^ (lane>>3)) + matching XOR on the ds_read side
// (phys slot = logical ^ (row&7)) -> 2-way conflicts only.
// EPI: 0=HID  bf16 NK [m_sp][1024] = hswish(acc + bias[n])
//      1=Y2   f32 CT [m_och][NPOS] = acc + bias[m] + bf16resNK[n][512]
//      2=PROJ f32 CT [m_och][perm(n)] = acc + bias[m] + f32resCT[same]
//      3=OUT  NCHW (bf16 or f32 per probe) = acc + bias[m] + f32resCT
// ---------------------------------------------------------------------------
template <int EPI, int K>
__global__ __launch_bounds__(256) void k_gemm(const hbf* __restrict__ A,
                                              const hbf* __restrict__ B,
                                              const hbf* __restrict__ bias,
                                              const void* __restrict__ res,
                                              void* __restrict__ out,
                                              const void* __restrict__ probe) {
    __shared__ short sA[128 * 64];   // 16 KB, linear 128B rows
    __shared__ short sB[128 * 64];

    const int tid = threadIdx.x;
    const int wave = tid >> 6, lane = tid & 63;
    const int col = lane & 15, quad = lane >> 4;
    const int m0 = blockIdx.x * 128, n0 = blockIdx.y * 128;
    const int wm = (wave & 1) * 64, wn = (wave >> 1) * 64;

    // staging: lane l of a wave-instruction covers row (base + l>>3),
    // phys slot l&7; global content slot = (l&7)^(l>>3)  [= phys ^ (row&7)]
    const int rowl = lane >> 3;
    const int kswz = ((lane & 7) ^ rowl) * 8;          // shorts
    const hbf* Ag = A + (size_t)(m0 + wave * 32 + rowl) * K + kswz;
    const hbf* Bg = B + (size_t)(n0 + wave * 32 + rowl) * K + kswz;
    short* sAw = sA + (wave * 32) * 64;                // wave's 32-row region
    short* sBw = sB + (wave * 32) * 64;

    f32x4 acc[4][4];
#pragma unroll
    for (int i = 0; i < 4; i++)
#pragma unroll
        for (int j = 0; j < 4; j++) acc[i][j] = (f32x4){0.f, 0.f, 0.f, 0.f};

    for (int k0 = 0; k0 < K; k0 += 64) {
        __syncthreads();                               // prev compute done
#pragma unroll
        for (int t = 0; t < 4; t++) {
            gl16(Ag + k0 + (size_t)t * 8 * K, sAw + t * 8 * 64);
            gl16(Bg + k0 + (size_t)t * 8 * K, sBw + t * 8 * 64);
        }
        __syncthreads();                               // vmcnt(0) drained here

#pragma unroll
        for (int kk = 0; kk < 2; kk++) {
            short8 af[4], bfr[4];
#pragma unroll
            for (int i = 0; i < 4; i++) {
                int r = wm + i * 16 + col;
                af[i] = *(const short8*)(sA + r * 64 + (((kk * 4 + quad) ^ (r & 7)) * 8));
            }
#pragma unroll
            for (int j = 0; j < 4; j++) {
                int r = wn + j * 16 + col;
                bfr[j] = *(const short8*)(sB + r * 64 + (((kk * 4 + quad) ^ (r & 7)) * 8));
            }
#pragma unroll
            for (int i = 0; i < 4; i++)
#pragma unroll
                for (int j = 0; j < 4; j++)
                    acc[i][j] = __builtin_amdgcn_mfma_f32_16x16x32_bf16(af[i], bfr[j], acc[i][j], 0, 0, 0);
        }
    }

    bool outbf = false;
    if constexpr (EPI == 3) outbf = is_bf16_buf(probe);

#pragma unroll
    for (int i = 0; i < 4; i++) {
#pragma unroll
        for (int j = 0; j < 4; j++) {
#pragma unroll
            for (int r = 0; r < 4; r++) {
                int mi = m0 + wm + i * 16 + quad * 4 + r;
                int nj = n0 + wn + j * 16 + col;
                float v = acc[i][j][r];
                if constexpr (EPI == 0) {
                    v = hswish(v + b2f(bias[nj]));
                    ((hbf*)out)[(size_t)mi * 1024 + nj] = f2b(v);
                } else if constexpr (EPI == 1) {
                    v += b2f(bias[mi]) + b2f(((const hbf*)res)[(size_t)nj * 512 + mi]);
                    ((float*)out)[(size_t)mi * NPOS + nj] = v;
                } else if constexpr (EPI == 2) {
                    int w = nj / 49, p = nj % 49;
                    int nct = (w >> 4) * 784 + (((w >> 2) & 3) * 7 + p / 7) * 28 + (w & 3) * 7 + p % 7;
                    size_t oi = (size_t)mi * NPOS + nct;
                    v += b2f(bias[mi]) + ((const float*)res)[oi];
                    ((float*)out)[oi] = v;
                } else {
                    int b = nj / 784, hw = nj % 784;
                    v += b2f(bias[mi]) + ((const float*)res)[(size_t)mi * NPOS + nj];
                    size_t oi = ((size_t)b * 512 + mi) * 784 + hw;
                    if (outbf) ((hbf*)out)[oi] = f2b(v);
                    else ((float*)out)[oi] = v;
                }
            }
        }
    }
}

// ---------------------------------------------------------------------------
// Depthwise 3x3 + residual, LDS-staged: coalesced float4 staging of
// [64ch][128pos] into LDS, branch-free stencil from LDS, register-held
// results, transpose tile aliases the stage.
// MODE 0: in = x NCHW (dtype per probe)  -> outNK
// MODE 1: in = x3f CT f32 -> outNK + outCT f32
// Positions staged: n0-32 .. n0+95. A float4 never straddles a batch boundary
// (784 % 4 == 0); clamped staging addresses are safe because the r/s masks
// guarantee out-of-image slots are never consumed.
// ---------------------------------------------------------------------------
template <int MODE, bool ISBF>
__device__ void dw_body(float* sIn, float* sW, const void* __restrict__ in,
                        const hbf* __restrict__ w, const hbf* __restrict__ bias,
                        hbf* __restrict__ outNK, float* __restrict__ outCT) {
    const int tid = threadIdx.x;
    const int tx = tid & 63, tg = tid >> 6;
    const int n0 = blockIdx.x * 64, c0 = blockIdx.y * 64;

    // ---- stage weights + bias: sW[cc*10 + t], t=9 is bias ----
    for (int e = tid; e < 640; e += 256) {
        int cc = e / 10, t = e - cc * 10;
        sW[e] = (t < 9) ? b2f(w[(c0 + cc) * 9 + t]) : b2f(bias[c0 + cc]);
    }

    // ---- stage input window sIn[64][128] f32 (8 x float4 per thread) ----
#pragma unroll
    for (int k = 0; k < 8; k++) {
        int idx = tid + k * 256;          // 2048 float4 slots
        int ch = idx >> 5, j4 = idx & 31;
        int p = n0 - 32 + j4 * 4;
        p = p < 0 ? 0 : (p > NPOS - 4 ? NPOS - 4 : p);
        f32x4 v;
        if constexpr (MODE == 1) {
            v = *(const f32x4*)((const float*)in + (size_t)(c0 + ch) * NPOS + p);
        } else {
            int b = p / 784, hw = p - b * 784;
            size_t ix = ((size_t)b * 512 + c0 + ch) * 784 + hw;
            if constexpr (ISBF) {
                bf16x4 t4 = *(const bf16x4*)((const hbf*)in + ix);
#pragma unroll
                for (int j = 0; j < 4; j++) {
                    unsigned u = (unsigned)(unsigned short)t4[j] << 16;
                    v[j] = __uint_as_float(u);
                }
            } else {
                v = *(const f32x4*)((const float*)in + ix);
            }
        }
        *(f32x4*)(sIn + ch * 128 + j4 * 4) = v;
    }
    __syncthreads();

    // ---- branch-free 3x3 stencil from LDS ----
    const int n = n0 + tx;
    const int b = n / 784, hw = n - b * 784;
    const int r = hw / 28, s = hw - r * 28;
    const float mrow[3] = { r > 0 ? 1.f : 0.f, 1.f, r < 27 ? 1.f : 0.f };
    const float mcol[3] = { s > 0 ? 1.f : 0.f, 1.f, s < 27 ? 1.f : 0.f };

    float vals[16];
#pragma unroll
    for (int i = 0; i < 16; i++) {
        const int cc = tg + 4 * i;
        const float* row = sIn + cc * 128 + 32 + tx;
        float acc = sW[cc * 10 + 9];
        float center = row[0];
#pragma unroll
        for (int dy = 0; dy < 3; dy++)
#pragma unroll
            for (int dx = 0; dx < 3; dx++)
                acc = fmaf(row[(dy - 1) * 28 + (dx - 1)],
                           mrow[dy] * mcol[dx] * sW[cc * 10 + dy * 3 + dx], acc);
        float val = center + acc;
        vals[i] = val;
        if constexpr (MODE == 1) outCT[(size_t)(c0 + cc) * NPOS + n] = val;
    }
    __syncthreads();

    // ---- transpose via LDS (aliases sIn) and write NK bf16 ----
    float (*tile)[65] = (float (*)[65])sIn;
#pragma unroll
    for (int i = 0; i < 16; i++) tile[tg + 4 * i][tx] = vals[i];
    __syncthreads();
    for (int q = tg; q < 64; q += 4)
        outNK[(size_t)(n0 + q) * 512 + c0 + tx] = f2b(tile[tx][q]);
}

template <int MODE>
__global__ __launch_bounds__(256, 4) void k_dw(const void* in, const hbf* w, const hbf* b,
                                               hbf* outNK, float* outCT, const void* probe) {
    __shared__ float sIn[64 * 128];   // 32 KB stage; transpose tile aliases it
    __shared__ float sW[64 * 10];
    if constexpr (MODE == 1) {
        dw_body<1, false>(sIn, sW, in, w, b, outNK, outCT);
    } else {
        if (is_bf16_buf(probe)) dw_body<0, true>(sIn, sW, in, w, b, outNK, outCT);
        else dw_body<0, false>(sIn, sW, in, w, b, outNK, outCT);
    }
}

// ---------------------------------------------------------------------------
// Cascade window attention, MFMA version. One block (4 waves) per 7x7 window;
// 8 heads sequential (data dependence). All GEMMs on the matrix pipe:
//   QKV:  yq[96][49] = w[96][64] . spT            (A=global bf16, B=spT LDS)
//   QK^T: att[49][49] = qT[49][16] . kT[49][16]   (K padded to 32 with zeros)
//   PV:   out[64][49] = vb[64][49] . atb[49][49]  (K padded to 64 with zeros)
// Softmax fully in-register (16-lane shfl_xor reduces). PV epilogue fuses the
// hswish->ywin global write and the next head's input tile (pv + y2 slice).
// T14: the next-head y2 residual reads are ISSUED at the top of each head
// iteration (regs), consumed in the PV epilogue -> HBM latency hides under
// the head's QKV/conv/QK/PV compute.
// ---------------------------------------------------------------------------
__global__ __launch_bounds__(256, 4) void k_attn(const float* __restrict__ y2,
                                                 const hbf* __restrict__ arena,
                                                 hbf* __restrict__ ywin) {
    __shared__ short spT[64 * 64];   // [n][c] bf16, swizzled 128B rows (B of QKV)
    __shared__ short vbT[64 * 64];   // [d][m] bf16, swizzled (A of PV); pad cols 0
    __shared__ short atb[64 * 64];   // [n][m] bf16, swizzled (B of PV); pad cols 0
    __shared__ short qT[64 * 40];    // [n][c] c<32, stride 40 (A of QK); c>=16 zero
    __shared__ short kT[64 * 40];    // [m][c] (B of QK); c>=16 zero
    __shared__ float qraw[16 * 52];  // [c][n] f32 conv staging
    __shared__ float abf[8 * 49];    // attn bias table f32

    const int tid = threadIdx.x;
    const int wave = tid >> 6, lane = tid & 63;
    const int col = lane & 15, quad = lane >> 4;
    const int w = blockIdx.x;
    const int wb = w >> 4, wh = (w >> 2) & 3, ww = w & 3;
    const size_t base = (size_t)wb * 784 + (wh * 7) * 28 + ww * 7;

    // one-time: zero MFMA pad regions (K-pads MUST be 0, and stay 0 because all
    // per-head writes are predicated to the valid <49/<16 range), stage bias.
    for (int e = tid; e < 64 * 64; e += 256) { vbT[e] = 0; atb[e] = 0; }
    for (int e = tid; e < 64 * 16; e += 256) {
        int n = e >> 4, c = 16 + (e & 15);
        qT[n * 40 + c] = 0; kT[n * 40 + c] = 0;
    }
    for (int e = tid; e < 8 * 49; e += 256) abf[e] = b2f(arena[OFF_AB + e]);

    // initial spT = spx[0] = y2 channels 0..63 of this window
    for (int e = tid; e < 64 * 49; e += 256) {
        int c = e / 49, n = e - c * 49;
        float v = y2[(size_t)c * NPOS + base + (n / 7) * 28 + (n % 7)];
        *(hbf*)((char*)spT + swz128(n, 2 * c)) = f2b(v);
    }

    // per-lane constants for C-frag epilogues (col=lane&15 -> out col n)
    int nj[4], posj[4], m7[4], mm7[4];
    bool vj[4];
#pragma unroll
    for (int j = 0; j < 4; j++) {
        nj[j] = j * 16 + col;
        vj[j] = nj[j] < 49;
        int nc = vj[j] ? nj[j] : 48;           // clamp so abf index stays in range
        m7[j] = nc / 7; mm7[j] = nc - m7[j] * 7;
        posj[j] = m7[j] * 28 + mm7[j];
    }
    const int nq = wave * 16 + quad * 4;       // C-frag out-row base for this lane

#pragma unroll 1
    for (int h = 0; h < 8; h++) {
        // ---- T14: issue next-head residual loads NOW, consume in epilogue ----
        float pre[4][4];
        if (h < 7) {
#pragma unroll
            for (int j = 0; j < 4; j++) {
                if (vj[j]) {
                    const float* ys = y2 + (size_t)((h + 1) * 64 + nq) * NPOS + base + posj[j];
#pragma unroll
                    for (int r = 0; r < 4; r++) pre[j][r] = ys[r * (size_t)NPOS];
                }
            }
        }
        __syncthreads();   // spT ready; prev-head vb/atb reads complete

        // ---- QKV GEMM: wave j owns output cols n = wave*16+col ----
        const hbf* wq = arena + OFF_QKVW + h * 96 * 64;
        const int brow = wave * 16 + col;
        short8 sb0 = *(const short8*)((const char*)spT + swz128(brow, quad * 16));
        short8 sb1 = *(const short8*)((const char*)spT + swz128(brow, 64 + quad * 16));
        f32x4 yacc[6];
#pragma unroll
        for (int i = 0; i < 6; i++) {
            short8 a0 = *(const short8*)(wq + (i * 16 + col) * 64 + quad * 8);
            short8 a1 = *(const short8*)(wq + (i * 16 + col) * 64 + 32 + quad * 8);
            f32x4 z = (f32x4){0.f, 0.f, 0.f, 0.f};
            z = __builtin_amdgcn_mfma_f32_16x16x32_bf16(a0, sb0, z, 0, 0, 0);
            z = __builtin_amdgcn_mfma_f32_16x16x32_bf16(a1, sb1, z, 0, 0, 0);
            yacc[i] = z;
        }
        // route: o<16 -> qraw f32; 16..31 -> kT bf16; 32..95 -> vbT bf16
        if (brow < 49) {
            const int n = brow;
#pragma unroll
            for (int i = 0; i < 6; i++) {
                float vv[4];
#pragma unroll
                for (int r = 0; r < 4; r++)
                    vv[r] = yacc[i][r] + b2f(arena[OFF_QKVB + h * 96 + i * 16 + quad * 4 + r]);
                if (i == 0) {
#pragma unroll
                    for (int r = 0; r < 4; r++) qraw[(quad * 4 + r) * 52 + n] = vv[r];
                } else if (i == 1) {
                    *(unsigned*)((char*)kT + n * 80 + 8 * quad)     = pk2(vv[0], vv[1]);
                    *(unsigned*)((char*)kT + n * 80 + 8 * quad + 4) = pk2(vv[2], vv[3]);
                } else {
#pragma unroll
                    for (int r = 0; r < 4; r++) {
                        int d = (i - 2) * 16 + quad * 4 + r;
                        *(hbf*)((char*)vbT + swz128(d, 2 * n)) = f2b(vv[r]);
                    }
                }
            }
        }
        __syncthreads();   // qraw, kT, vbT ready

        // ---- depthwise conv on q (scalar, all 256 threads on 784 items) ----
        const hbf* cw; const hbf* cb; int ks;
        if (h == 0)      { cw = arena + OFF_W7; cb = arena + OFF_B7; ks = 7; }
        else if (h == 1) { cw = arena + OFF_W5; cb = arena + OFF_B5; ks = 5; }
        else             { cw = arena + OFF_W3 + (h - 2) * 144; cb = arena + OFF_B3 + (h - 2) * 16; ks = 3; }
        const int pad = ks >> 1;
        for (int e = tid; e < 784; e += 256) {
            int c = e / 49, n = e - c * 49;
            int r = n / 7, s = n - r * 7;
            float acc = b2f(cb[c]);
            for (int dy = 0; dy < ks; dy++) {
                int rr = r + dy - pad;
                if (rr < 0 || rr >= 7) continue;
                for (int dx = 0; dx < ks; dx++) {
                    int ss = s + dx - pad;
                    if (ss < 0 || ss >= 7) continue;
                    acc += b2f(cw[c * ks * ks + dy * ks + dx]) * qraw[c * 52 + rr * 7 + ss];
                }
            }
            // fold SCALE = 0.25 (exact) into q before bf16 quantization
            *(hbf*)((char*)qT + n * 80 + 2 * c) = f2b(acc * 0.25f);
        }
        __syncthreads();   // qT ready

        // ---- QK^T (wave i owns att rows i*16..i*16+15) + in-register softmax ----
        short8 qa = *(const short8*)((const char*)qT + (wave * 16 + col) * 80 + quad * 16);
        f32x4 sat[4];
#pragma unroll
        for (int j = 0; j < 4; j++) {
            short8 kb = *(const short8*)((const char*)kT + (j * 16 + col) * 80 + quad * 16);
            f32x4 z = (f32x4){0.f, 0.f, 0.f, 0.f};
            sat[j] = __builtin_amdgcn_mfma_f32_16x16x32_bf16(qa, kb, z, 0, 0, 0);
        }
#pragma unroll
        for (int r = 0; r < 4; r++) {
            int n = nq + r;                       // att row (>=49 rows are junk, never consumed)
            int ncl = n < 49 ? n : 48;
            int n7 = ncl / 7, nn7 = ncl - n7 * 7;
            float v0 = sat[0][r] + abf[h * 49 + abs(n7 - m7[0]) * 7 + abs(nn7 - mm7[0])];
            float v1 = sat[1][r] + abf[h * 49 + abs(n7 - m7[1]) * 7 + abs(nn7 - mm7[1])];
            float v2 = sat[2][r] + abf[h * 49 + abs(n7 - m7[2]) * 7 + abs(nn7 - mm7[2])];
            float v3 = (col == 0) ? sat[3][r] + abf[h * 49 + abs(n7 - m7[3]) * 7 + abs(nn7 - mm7[3])]
                                  : -1e30f;      // m = 48+col valid only at col==0
            float mx = fmaxf(fmaxf(v0, v1), fmaxf(v2, v3));
#pragma unroll
            for (int s = 1; s < 16; s <<= 1) mx = fmaxf(mx, __shfl_xor(mx, s));
            float p0 = __expf(v0 - mx), p1 = __expf(v1 - mx), p2 = __expf(v2 - mx);
            float p3 = (col == 0) ? __expf(v3 - mx) : 0.f;
            float sm = p0 + p1 + p2 + p3;
#pragma unroll
            for (int s = 1; s < 16; s <<= 1) sm += __shfl_xor(sm, s);
            float inv = 1.0f / sm;
            *(hbf*)((char*)atb + swz128(n, 2 * col))        = f2b(p0 * inv);
            *(hbf*)((char*)atb + swz128(n, 2 * (16 + col))) = f2b(p1 * inv);
            *(hbf*)((char*)atb + swz128(n, 2 * (32 + col))) = f2b(p2 * inv);
            if (col == 0) *(hbf*)((char*)atb + swz128(n, 2 * 48)) = f2b(p3 * inv);
        }
        __syncthreads();   // atb ready

        // ---- PV (wave i owns out rows d = wave*16..+15) + fused epilogue ----
        short8 va0 = *(const short8*)((const char*)vbT + swz128(wave * 16 + col, quad * 16));
        short8 va1 = *(const short8*)((const char*)vbT + swz128(wave * 16 + col, 64 + quad * 16));
#pragma unroll
        for (int j = 0; j < 4; j++) {
            short8 pb0 = *(const short8*)((const char*)atb + swz128(nj[j], quad * 16));
            short8 pb1 = *(const short8*)((const char*)atb + swz128(nj[j], 64 + quad * 16));
            f32x4 o = (f32x4){0.f, 0.f, 0.f, 0.f};
            o = __builtin_amdgcn_mfma_f32_16x16x32_bf16(va0, pb0, o, 0, 0, 0);
            o = __builtin_amdgcn_mfma_f32_16x16x32_bf16(va1, pb1, o, 0, 0, 0);
            if (vj[j]) {
                size_t yo = ((size_t)w * 49 + nj[j]) * 512 + h * 64 + nq;
                *(unsigned*)(ywin + yo)     = pk2(hswish(o[0]), hswish(o[1]));
                *(unsigned*)(ywin + yo + 2) = pk2(hswish(o[2]), hswish(o[3]));
                if (h < 7) {   // next head input: pv + spx[h+1] (prefetched)
                    unsigned s0 = pk2(o[0] + pre[j][0], o[1] + pre[j][1]);
                    unsigned s1 = pk2(o[2] + pre[j][2], o[3] + pre[j][3]);
                    *(unsigned*)((char*)spT + swz128(nj[j], 2 * nq))     = s0;
                    *(unsigned*)((char*)spT + swz128(nj[j], 2 * nq + 4)) = s1;
                }
            }
        }
    }
}

// ---------------------------------------------------------------------------

extern "C" void kernel_launch(void* const* d_in, const int* in_sizes, int n_in,
                              void* d_out, int out_size, void* d_ws, size_t ws_size,
                              hipStream_t stream) {
    const void* x = d_in[0];

    if (ws_size < NEL * 10 + (size_t)ARENA_TOT * 2) return;

    uint8_t* p = (uint8_t*)d_ws;
    hbf*   R0 = (hbf*)p;                          // NEL bf16
    hbf*   R1 = (hbf*)(p + NEL * 2);              // NEL*4 bytes
    float* R2 = (float*)(p + NEL * 6);            // NEL f32
    hbf*   arena = (hbf*)(p + NEL * 10);

    hbf*   y1t  = R0;
    hbf*   hid  = R1;
    float* y2f  = R2;
    hbf*   ywin = R0;
    float* x3f  = (float*)R1;
    float* x4f  = R2;
    hbf*   x4t  = R0;
    hbf*   hid2 = R1;

    CvtTable tab = {{
        { d_in[3],  OFF_W01,  524288 },  // ffn0_w1
        { d_in[5],  OFF_W02,  524288 },  // ffn0_w2
        { d_in[20], OFF_W11,  524288 },  // ffn1_w1
        { d_in[22], OFF_W12,  524288 },  // ffn1_w2
        { d_in[16], OFF_PW,   262144 },  // proj_w
        { d_in[7],  OFF_QKVW, 49152 },   // qkv_w
        { d_in[8],  OFF_QKVB, 768 },     // qkv_b
        { d_in[9],  OFF_W7,   784 },
        { d_in[10], OFF_B7,   16 },
        { d_in[11], OFF_W5,   400 },
        { d_in[12], OFF_B5,   16 },
        { d_in[13], OFF_W3,   864 },
        { d_in[14], OFF_B3,   96 },
        { d_in[15], OFF_AB,   392 },
        { d_in[1],  OFF_D0W,  4608 },
        { d_in[2],  OFF_D0B,  512 },
        { d_in[18], OFF_D1W,  4608 },
        { d_in[19], OFF_D1B,  512 },
        { d_in[4],  OFF_B01,  1024 },
        { d_in[6],  OFF_B02,  512 },
        { d_in[21], OFF_B11,  1024 },
        { d_in[23], OFF_B12,  512 },
        { d_in[17], OFF_PB,   512 },
    }};

    dim3 blk(256);

    // 0. convert all weights/biases to bf16 arena
    k_convert<<<dim3(2048, 23), blk, 0, stream>>>(tab, arena, x);
    // 1. y1t = (x + dw0(x)) NK bf16
    k_dw<0><<<dim3(NPOS / 64, 8), blk, 0, stream>>>(x, arena + OFF_D0W, arena + OFF_D0B, y1t, nullptr, x);
    // 2. hid = hswish(y1t @ ffn0_w1^T)  NK bf16 [NPOS][1024]
    k_gemm<0, 512><<<dim3(392, 8), blk, 0, stream>>>(y1t, arena + OFF_W01, arena + OFF_B01, nullptr, hid, x);
    // 3. y2f = y1 + hid @ ffn0_w2^T  CT f32
    k_gemm<1, 1024><<<dim3(4, 392), blk, 0, stream>>>(arena + OFF_W02, hid, arena + OFF_B02, y1t, y2f, x);
    // 4. attention -> ywin NK bf16 (hswish applied)
    k_attn<<<1024, blk, 0, stream>>>(y2f, arena, ywin);
    // 5. x3f = y2 + merge(ywin @ proj_w^T)  CT f32
    k_gemm<2, 512><<<dim3(4, 392), blk, 0, stream>>>(arena + OFF_PW, ywin, arena + OFF_PB, y2f, x3f, x);
    // 6. x4f CT f32 + x4t NK bf16 = x3 + dw1(x3)
    k_dw<1><<<dim3(NPOS / 64, 8), blk, 0, stream>>>(x3f, arena + OFF_D1W, arena + OFF_D1B, x4t, x4f, x);
    // 7. hid2 = hswish(x4t @ ffn1_w1^T)
    k_gemm<0, 512><<<dim3(392, 8), blk, 0, stream>>>(x4t, arena + OFF_W11, arena + OFF_B11, nullptr, hid2, x);
    // 8. out = x4 + hid2 @ ffn1_w2^T  NCHW (dtype per probe)
    k_gemm<3, 1024><<<dim3(4, 392), blk, 0, stream>>>(arena + OFF_W12, hid2, arena + OFF_B12, x4f, d_out, x);
}

// Round 5
// 1029.267 us; speedup vs baseline: 1.8758x; 1.1070x over previous
//
#include <hip/hip_runtime.h>
#include <hip/hip_bf16.h>

// ---------------------------------------------------------------------------
// BasicBlock (EfficientViT-style) on MI355X. Input dtype (fp32 vs bf16) is
// runtime-detected; all weights are pre-converted into a bf16 arena in ws so
// the compute kernels are dtype-free. GEMMs: bf16 MFMA, fp32 accum.
//
// Layouts:
//   CT = [C][N]  n-contiguous (N = 50176 = 64*784) fp32, residuals/attn in.
//   NK = [N][K]  k-contiguous bf16, MFMA GEMM operands (ds_read_b128 frags).
// ---------------------------------------------------------------------------

#define NPOS 50176                  // 64 * 784
#define NEL ((size_t)512 * NPOS)

typedef __hip_bfloat16 hbf;
typedef unsigned int u32;
typedef __attribute__((ext_vector_type(8))) short short8;   // 8 bf16
typedef __attribute__((ext_vector_type(4))) short bf16x4;   // 4 bf16
typedef __attribute__((ext_vector_type(4))) float f32x4;

__device__ __forceinline__ float hswish(float v) {
    float t = fminf(fmaxf(v + 3.0f, 0.0f), 6.0f);
    return v * t * (1.0f / 6.0f);
}
__device__ __forceinline__ float b2f(hbf x) { return __bfloat162float(x); }
__device__ __forceinline__ hbf f2b(float x) { return __float2bfloat16(x); }

__device__ __forceinline__ unsigned short bfb(float v) {
    hbf h = f2b(v); unsigned short u; __builtin_memcpy(&u, &h, 2); return u;
}
__device__ __forceinline__ unsigned pk2(float a, float b) {
    return (unsigned)bfb(a) | ((unsigned)bfb(b) << 16);
}
// byte address into a [row][64 bf16] (=128B rows) LDS array, XOR-swizzled so
// that column-slice ds_read_b128 across 16 lanes is ~2-way conflict free.
__device__ __forceinline__ int swz128(int row, int b) {
    return row * 128 + (b ^ ((row & 7) << 4));
}
// async global->LDS, 16B per lane. LDS dest = uniform base + lane*16.
__device__ __forceinline__ void gl16(const hbf* g, short* l) {
    __builtin_amdgcn_global_load_lds((const __attribute__((address_space(1))) u32*)g,
                                     (__attribute__((address_space(3))) u32*)l,
                                     16, 0, 0);
}

// Probe x's dtype: low 16 bits of fp32 words are random mantissa bits (~16%
// "sane bf16 exponent" rate); in a packed-bf16 buffer they are real bf16
// values (~100%). 64 words, threshold 32 -> error prob < 1e-10.
__device__ __forceinline__ bool is_bf16_buf(const void* probe) {
    const unsigned* w = (const unsigned*)probe;
    int hits = 0;
#pragma unroll
    for (int i = 0; i < 64; i++) {
        unsigned lo = w[i] & 0xFFFFu;
        unsigned e = (lo >> 7) & 0xFFu;
        hits += ((e >= 100u && e <= 140u) || lo == 0u) ? 1 : 0;
    }
    return hits >= 32;
}

// ---------------------------------------------------------------------------
// Weight arena (bf16) — compile-time element offsets.
// ---------------------------------------------------------------------------
#define OFF_W01  0          // ffn0_w1 [1024][512]
#define OFF_W02  524288     // ffn0_w2 [512][1024]
#define OFF_W11  1048576    // ffn1_w1 [1024][512]
#define OFF_W12  1572864    // ffn1_w2 [512][1024]
#define OFF_PW   2097152    // proj_w  [512][512]
#define OFF_QKVW 2359296    // qkv_w   [8][96][64]
#define OFF_QKVB 2408448    // qkv_b   [8][96]
#define OFF_W7   2409216
#define OFF_B7   2410000
#define OFF_W5   2410016
#define OFF_B5   2410416
#define OFF_W3   2410432    // [6][16][9]
#define OFF_B3   2411296    // [6][16]
#define OFF_AB   2411392    // [8][49]
#define OFF_D0W  2411784    // dw0_w [512][9]
#define OFF_D0B  2416392
#define OFF_D1W  2416904
#define OFF_D1B  2421512
#define OFF_B01  2422024    // ffn0_b1 [1024]
#define OFF_B02  2423048
#define OFF_B11  2423560
#define OFF_B12  2424584
#define OFF_PB   2425096
#define ARENA_TOT 2425608

struct CvtArgs { const void* src; int off; int count; };
struct CvtTable { CvtArgs t[23]; };

__global__ __launch_bounds__(256) void k_convert(CvtTable tab, hbf* __restrict__ arena,
                                                 const void* __restrict__ probe) {
    CvtArgs a = tab.t[blockIdx.y];
    int i = blockIdx.x * 256 + threadIdx.x;
    if (i >= a.count) return;            // bounds-check BEFORE the 64-load probe
    bool isbf = is_bf16_buf(probe);
    float v = isbf ? b2f(((const hbf*)a.src)[i]) : ((const float*)a.src)[i];
    arena[a.off + i] = f2b(v);
}

// ---------------------------------------------------------------------------
// MFMA GEMM: D[m][n] = A[m][:] . B[n][:]  (both k-contiguous rows, bf16)
// m97 structure: 128x128 tile, BK=64, 4 waves, 4x4 frags, 16x16x32 MFMA.
// Staging is pure global_load_lds (dwordx4): LDS [128 rows][8 x 16B slots]
// linear; bank-conflict fix per Rule 21 = pre-swizzled GLOBAL source
// (slot_logical = (lane&7) ^ (lane>>3)) + matching XOR on the ds_read side.
//
// Block mapping: bijective XCD swizzle (m157/m204, nwg%8==0 in all launches)
// so consecutive LOGICAL tiles land on the SAME XCD's L2. SWAP flips the
// (x,y)->(m,n) roles so the fast-varying logical axis is the one sharing the
// LARGE operand tile (EPI0: 8 n-tiles share one A-tile -> A read once).
// EPI: 0=HID  bf16 NK [m_sp][1024] = hswish(acc + bias[n])
//      1=Y2   f32 CT [m_och][NPOS] = acc + bias[m] + bf16resNK[n][512]
//      2=PROJ f32 CT [m_och][perm(n)] = acc + bias[m] + f32resCT[same]
//      3=OUT  NCHW (bf16 or f32 per probe) = acc + bias[m] + f32resCT
// ---------------------------------------------------------------------------
template <int EPI, int K, int GX, bool SWAP>
__global__ __launch_bounds__(256) void k_gemm(const hbf* __restrict__ A,
                                              const hbf* __restrict__ B,
                                              const hbf* __restrict__ bias,
                                              const void* __restrict__ res,
                                              void* __restrict__ out,
                                              const void* __restrict__ probe) {
    __shared__ short sA[128 * 64];   // 16 KB, linear 128B rows
    __shared__ short sB[128 * 64];

    const int tid = threadIdx.x;
    const int wave = tid >> 6, lane = tid & 63;
    const int col = lane & 15, quad = lane >> 4;

    // XCD-aware bijective block swizzle: physical id -> logical tile id
    const int lin = blockIdx.y * GX + blockIdx.x;
    const int q8 = (GX * (int)gridDim.y) >> 3;        // nwg/8 (nwg%8==0)
    const int swz = (lin & 7) * q8 + (lin >> 3);
    const int bx = swz % GX, by = swz / GX;
    const int m0 = (SWAP ? by : bx) * 128, n0 = (SWAP ? bx : by) * 128;

    const int wm = (wave & 1) * 64, wn = (wave >> 1) * 64;

    // staging: lane l covers row (base + l>>3), phys slot l&7;
    // global content slot = (l&7)^(l>>3)  [= phys ^ (row&7)]
    const int rowl = lane >> 3;
    const int kswz = ((lane & 7) ^ rowl) * 8;          // shorts
    const hbf* Ag = A + (size_t)(m0 + wave * 32 + rowl) * K + kswz;
    const hbf* Bg = B + (size_t)(n0 + wave * 32 + rowl) * K + kswz;
    short* sAw = sA + (wave * 32) * 64;                // wave's 32-row region
    short* sBw = sB + (wave * 32) * 64;

    f32x4 acc[4][4];
#pragma unroll
    for (int i = 0; i < 4; i++)
#pragma unroll
        for (int j = 0; j < 4; j++) acc[i][j] = (f32x4){0.f, 0.f, 0.f, 0.f};

    for (int k0 = 0; k0 < K; k0 += 64) {
        __syncthreads();                               // prev compute done
#pragma unroll
        for (int t = 0; t < 4; t++) {
            gl16(Ag + k0 + (size_t)t * 8 * K, sAw + t * 8 * 64);
            gl16(Bg + k0 + (size_t)t * 8 * K, sBw + t * 8 * 64);
        }
        __syncthreads();                               // vmcnt(0) drained here

#pragma unroll
        for (int kk = 0; kk < 2; kk++) {
            short8 af[4], bfr[4];
#pragma unroll
            for (int i = 0; i < 4; i++) {
                int r = wm + i * 16 + col;
                af[i] = *(const short8*)(sA + r * 64 + (((kk * 4 + quad) ^ (r & 7)) * 8));
            }
#pragma unroll
            for (int j = 0; j < 4; j++) {
                int r = wn + j * 16 + col;
                bfr[j] = *(const short8*)(sB + r * 64 + (((kk * 4 + quad) ^ (r & 7)) * 8));
            }
#pragma unroll
            for (int i = 0; i < 4; i++)
#pragma unroll
                for (int j = 0; j < 4; j++)
                    acc[i][j] = __builtin_amdgcn_mfma_f32_16x16x32_bf16(af[i], bfr[j], acc[i][j], 0, 0, 0);
        }
    }

    bool outbf = false;
    if constexpr (EPI == 3) outbf = is_bf16_buf(probe);

#pragma unroll
    for (int i = 0; i < 4; i++) {
#pragma unroll
        for (int j = 0; j < 4; j++) {
#pragma unroll
            for (int r = 0; r < 4; r++) {
                int mi = m0 + wm + i * 16 + quad * 4 + r;
                int nj = n0 + wn + j * 16 + col;
                float v = acc[i][j][r];
                if constexpr (EPI == 0) {
                    v = hswish(v + b2f(bias[nj]));
                    ((hbf*)out)[(size_t)mi * 1024 + nj] = f2b(v);
                } else if constexpr (EPI == 1) {
                    v += b2f(bias[mi]) + b2f(((const hbf*)res)[(size_t)nj * 512 + mi]);
                    ((float*)out)[(size_t)mi * NPOS + nj] = v;
                } else if constexpr (EPI == 2) {
                    int w = nj / 49, p = nj % 49;
                    int nct = (w >> 4) * 784 + (((w >> 2) & 3) * 7 + p / 7) * 28 + (w & 3) * 7 + p % 7;
                    size_t oi = (size_t)mi * NPOS + nct;
                    v += b2f(bias[mi]) + ((const float*)res)[oi];
                    ((float*)out)[oi] = v;
                } else {
                    int b = nj / 784, hw = nj % 784;
                    v += b2f(bias[mi]) + ((const float*)res)[(size_t)mi * NPOS + nj];
                    size_t oi = ((size_t)b * 512 + mi) * 784 + hw;
                    if (outbf) ((hbf*)out)[oi] = f2b(v);
                    else ((float*)out)[oi] = v;
                }
            }
        }
    }
}

// ---------------------------------------------------------------------------
// Depthwise 3x3 + residual, LDS-staged: coalesced float4 staging of
// [64ch][128pos] into LDS, branch-free stencil from LDS, register-held
// results, transpose tile aliases the stage.
// MODE 0: in = x NCHW (dtype per probe)  -> outNK
// MODE 1: in = x3f CT f32 -> outNK + outCT f32
// ---------------------------------------------------------------------------
template <int MODE, bool ISBF>
__device__ void dw_body(float* sIn, float* sW, const void* __restrict__ in,
                        const hbf* __restrict__ w, const hbf* __restrict__ bias,
                        hbf* __restrict__ outNK, float* __restrict__ outCT) {
    const int tid = threadIdx.x;
    const int tx = tid & 63, tg = tid >> 6;
    const int n0 = blockIdx.x * 64, c0 = blockIdx.y * 64;

    // ---- stage weights + bias: sW[cc*10 + t], t=9 is bias ----
    for (int e = tid; e < 640; e += 256) {
        int cc = e / 10, t = e - cc * 10;
        sW[e] = (t < 9) ? b2f(w[(c0 + cc) * 9 + t]) : b2f(bias[c0 + cc]);
    }

    // ---- stage input window sIn[64][128] f32 (8 x float4 per thread) ----
#pragma unroll
    for (int k = 0; k < 8; k++) {
        int idx = tid + k * 256;          // 2048 float4 slots
        int ch = idx >> 5, j4 = idx & 31;
        int p = n0 - 32 + j4 * 4;
        p = p < 0 ? 0 : (p > NPOS - 4 ? NPOS - 4 : p);
        f32x4 v;
        if constexpr (MODE == 1) {
            v = *(const f32x4*)((const float*)in + (size_t)(c0 + ch) * NPOS + p);
        } else {
            int b = p / 784, hw = p - b * 784;
            size_t ix = ((size_t)b * 512 + c0 + ch) * 784 + hw;
            if constexpr (ISBF) {
                bf16x4 t4 = *(const bf16x4*)((const hbf*)in + ix);
#pragma unroll
                for (int j = 0; j < 4; j++) {
                    unsigned u = (unsigned)(unsigned short)t4[j] << 16;
                    v[j] = __uint_as_float(u);
                }
            } else {
                v = *(const f32x4*)((const float*)in + ix);
            }
        }
        *(f32x4*)(sIn + ch * 128 + j4 * 4) = v;
    }
    __syncthreads();

    // ---- branch-free 3x3 stencil from LDS ----
    const int n = n0 + tx;
    const int b = n / 784, hw = n - b * 784;
    const int r = hw / 28, s = hw - r * 28;
    const float mrow[3] = { r > 0 ? 1.f : 0.f, 1.f, r < 27 ? 1.f : 0.f };
    const float mcol[3] = { s > 0 ? 1.f : 0.f, 1.f, s < 27 ? 1.f : 0.f };

    float vals[16];
#pragma unroll
    for (int i = 0; i < 16; i++) {
        const int cc = tg + 4 * i;
        const float* row = sIn + cc * 128 + 32 + tx;
        float acc = sW[cc * 10 + 9];
        float center = row[0];
#pragma unroll
        for (int dy = 0; dy < 3; dy++)
#pragma unroll
            for (int dx = 0; dx < 3; dx++)
                acc = fmaf(row[(dy - 1) * 28 + (dx - 1)],
                           mrow[dy] * mcol[dx] * sW[cc * 10 + dy * 3 + dx], acc);
        float val = center + acc;
        vals[i] = val;
        if constexpr (MODE == 1) outCT[(size_t)(c0 + cc) * NPOS + n] = val;
    }
    __syncthreads();

    // ---- transpose via LDS (aliases sIn) and write NK bf16 ----
    float (*tile)[65] = (float (*)[65])sIn;
#pragma unroll
    for (int i = 0; i < 16; i++) tile[tg + 4 * i][tx] = vals[i];
    __syncthreads();
    for (int q = tg; q < 64; q += 4)
        outNK[(size_t)(n0 + q) * 512 + c0 + tx] = f2b(tile[tx][q]);
}

template <int MODE>
__global__ __launch_bounds__(256, 4) void k_dw(const void* in, const hbf* w, const hbf* b,
                                               hbf* outNK, float* outCT, const void* probe) {
    __shared__ float sIn[64 * 128];   // 32 KB stage; transpose tile aliases it
    __shared__ float sW[64 * 10];
    if constexpr (MODE == 1) {
        dw_body<1, false>(sIn, sW, in, w, b, outNK, outCT);
    } else {
        if (is_bf16_buf(probe)) dw_body<0, true>(sIn, sW, in, w, b, outNK, outCT);
        else dw_body<0, false>(sIn, sW, in, w, b, outNK, outCT);
    }
}

// ---------------------------------------------------------------------------
// Cascade window attention, MFMA version. One block (4 waves) per 7x7 window;
// 8 heads sequential (data dependence). All GEMMs on the matrix pipe:
//   QKV:  yq[96][49] = w[96][64] . spT            (A=global bf16, B=spT LDS)
//   QK^T: att[49][49] = qT[49][16] . kT[49][16]   (K padded to 32 with zeros)
//   PV:   out[64][49] = vb[64][49] . atb[49][49]  (K padded to 64 with zeros)
// Softmax fully in-register (16-lane shfl_xor reduces). PV epilogue fuses the
// hswish->ywin global write and the next head's input tile (pv + y2 slice).
// Window id XCD-swizzled so spatially-adjacent windows (which share y2
// cachelines at window boundaries) land on the same XCD's L2.
// ---------------------------------------------------------------------------
__global__ __launch_bounds__(256, 4) void k_attn(const float* __restrict__ y2,
                                                 const hbf* __restrict__ arena,
                                                 hbf* __restrict__ ywin) {
    __shared__ short spT[64 * 64];   // [n][c] bf16, swizzled 128B rows (B of QKV)
    __shared__ short vbT[64 * 64];   // [d][m] bf16, swizzled (A of PV); pad cols 0
    __shared__ short atb[64 * 64];   // [n][m] bf16, swizzled (B of PV); pad cols 0
    __shared__ short qT[64 * 40];    // [n][c] c<32, stride 40 (A of QK); c>=16 zero
    __shared__ short kT[64 * 40];    // [m][c] (B of QK); c>=16 zero
    __shared__ float qraw[16 * 52];  // [c][n] f32 conv staging
    __shared__ float abf[8 * 49];    // attn bias table f32

    const int tid = threadIdx.x;
    const int wave = tid >> 6, lane = tid & 63;
    const int col = lane & 15, quad = lane >> 4;
    const int w = ((blockIdx.x & 7) << 7) | (blockIdx.x >> 3);   // XCD swizzle
    const int wb = w >> 4, wh = (w >> 2) & 3, ww = w & 3;
    const size_t base = (size_t)wb * 784 + (wh * 7) * 28 + ww * 7;

    // one-time: zero MFMA pad regions (K-pads MUST be 0, and stay 0 because all
    // per-head writes are predicated to the valid <49/<16 range), stage bias.
    for (int e = tid; e < 64 * 64; e += 256) { vbT[e] = 0; atb[e] = 0; }
    for (int e = tid; e < 64 * 16; e += 256) {
        int n = e >> 4, c = 16 + (e & 15);
        qT[n * 40 + c] = 0; kT[n * 40 + c] = 0;
    }
    for (int e = tid; e < 8 * 49; e += 256) abf[e] = b2f(arena[OFF_AB + e]);

    // initial spT = spx[0] = y2 channels 0..63 of this window
    for (int e = tid; e < 64 * 49; e += 256) {
        int c = e / 49, n = e - c * 49;
        float v = y2[(size_t)c * NPOS + base + (n / 7) * 28 + (n % 7)];
        *(hbf*)((char*)spT + swz128(n, 2 * c)) = f2b(v);
    }

    // per-lane constants for C-frag epilogues (col=lane&15 -> out col n)
    int nj[4], posj[4], m7[4], mm7[4];
    bool vj[4];
#pragma unroll
    for (int j = 0; j < 4; j++) {
        nj[j] = j * 16 + col;
        vj[j] = nj[j] < 49;
        int nc = vj[j] ? nj[j] : 48;           // clamp so abf index stays in range
        m7[j] = nc / 7; mm7[j] = nc - m7[j] * 7;
        posj[j] = m7[j] * 28 + mm7[j];
    }
    const int nq = wave * 16 + quad * 4;       // C-frag out-row base for this lane

#pragma unroll 1
    for (int h = 0; h < 8; h++) {
        __syncthreads();   // spT ready; prev-head vb/atb reads complete

        // ---- QKV GEMM: wave j owns output cols n = wave*16+col ----
        const hbf* wq = arena + OFF_QKVW + h * 96 * 64;
        const int brow = wave * 16 + col;
        short8 sb0 = *(const short8*)((const char*)spT + swz128(brow, quad * 16));
        short8 sb1 = *(const short8*)((const char*)spT + swz128(brow, 64 + quad * 16));
        f32x4 yacc[6];
#pragma unroll
        for (int i = 0; i < 6; i++) {
            short8 a0 = *(const short8*)(wq + (i * 16 + col) * 64 + quad * 8);
            short8 a1 = *(const short8*)(wq + (i * 16 + col) * 64 + 32 + quad * 8);
            f32x4 z = (f32x4){0.f, 0.f, 0.f, 0.f};
            z = __builtin_amdgcn_mfma_f32_16x16x32_bf16(a0, sb0, z, 0, 0, 0);
            z = __builtin_amdgcn_mfma_f32_16x16x32_bf16(a1, sb1, z, 0, 0, 0);
            yacc[i] = z;
        }
        // route: o<16 -> qraw f32; 16..31 -> kT bf16; 32..95 -> vbT bf16
        if (brow < 49) {
            const int n = brow;
#pragma unroll
            for (int i = 0; i < 6; i++) {
                float vv[4];
#pragma unroll
                for (int r = 0; r < 4; r++)
                    vv[r] = yacc[i][r] + b2f(arena[OFF_QKVB + h * 96 + i * 16 + quad * 4 + r]);
                if (i == 0) {
#pragma unroll
                    for (int r = 0; r < 4; r++) qraw[(quad * 4 + r) * 52 + n] = vv[r];
                } else if (i == 1) {
                    *(unsigned*)((char*)kT + n * 80 + 8 * quad)     = pk2(vv[0], vv[1]);
                    *(unsigned*)((char*)kT + n * 80 + 8 * quad + 4) = pk2(vv[2], vv[3]);
                } else {
#pragma unroll
                    for (int r = 0; r < 4; r++) {
                        int d = (i - 2) * 16 + quad * 4 + r;
                        *(hbf*)((char*)vbT + swz128(d, 2 * n)) = f2b(vv[r]);
                    }
                }
            }
        }
        __syncthreads();   // qraw, kT, vbT ready

        // ---- depthwise conv on q (scalar, all 256 threads on 784 items) ----
        const hbf* cw; const hbf* cb; int ks;
        if (h == 0)      { cw = arena + OFF_W7; cb = arena + OFF_B7; ks = 7; }
        else if (h == 1) { cw = arena + OFF_W5; cb = arena + OFF_B5; ks = 5; }
        else             { cw = arena + OFF_W3 + (h - 2) * 144; cb = arena + OFF_B3 + (h - 2) * 16; ks = 3; }
        const int pad = ks >> 1;
        for (int e = tid; e < 784; e += 256) {
            int c = e / 49, n = e - c * 49;
            int r = n / 7, s = n - r * 7;
            float acc = b2f(cb[c]);
            for (int dy = 0; dy < ks; dy++) {
                int rr = r + dy - pad;
                if (rr < 0 || rr >= 7) continue;
                for (int dx = 0; dx < ks; dx++) {
                    int ss = s + dx - pad;
                    if (ss < 0 || ss >= 7) continue;
                    acc += b2f(cw[c * ks * ks + dy * ks + dx]) * qraw[c * 52 + rr * 7 + ss];
                }
            }
            // fold SCALE = 0.25 (exact) into q before bf16 quantization
            *(hbf*)((char*)qT + n * 80 + 2 * c) = f2b(acc * 0.25f);
        }
        __syncthreads();   // qT ready

        // ---- QK^T (wave i owns att rows i*16..i*16+15) + in-register softmax ----
        short8 qa = *(const short8*)((const char*)qT + (wave * 16 + col) * 80 + quad * 16);
        f32x4 sat[4];
#pragma unroll
        for (int j = 0; j < 4; j++) {
            short8 kb = *(const short8*)((const char*)kT + (j * 16 + col) * 80 + quad * 16);
            f32x4 z = (f32x4){0.f, 0.f, 0.f, 0.f};
            sat[j] = __builtin_amdgcn_mfma_f32_16x16x32_bf16(qa, kb, z, 0, 0, 0);
        }
#pragma unroll
        for (int r = 0; r < 4; r++) {
            int n = nq + r;                       // att row (>=49 rows are junk, never consumed)
            int ncl = n < 49 ? n : 48;
            int n7 = ncl / 7, nn7 = ncl - n7 * 7;
            float v0 = sat[0][r] + abf[h * 49 + abs(n7 - m7[0]) * 7 + abs(nn7 - mm7[0])];
            float v1 = sat[1][r] + abf[h * 49 + abs(n7 - m7[1]) * 7 + abs(nn7 - mm7[1])];
            float v2 = sat[2][r] + abf[h * 49 + abs(n7 - m7[2]) * 7 + abs(nn7 - mm7[2])];
            float v3 = (col == 0) ? sat[3][r] + abf[h * 49 + abs(n7 - m7[3]) * 7 + abs(nn7 - mm7[3])]
                                  : -1e30f;      // m = 48+col valid only at col==0
            float mx = fmaxf(fmaxf(v0, v1), fmaxf(v2, v3));
#pragma unroll
            for (int s = 1; s < 16; s <<= 1) mx = fmaxf(mx, __shfl_xor(mx, s));
            float p0 = __expf(v0 - mx), p1 = __expf(v1 - mx), p2 = __expf(v2 - mx);
            float p3 = (col == 0) ? __expf(v3 - mx) : 0.f;
            float sm = p0 + p1 + p2 + p3;
#pragma unroll
            for (int s = 1; s < 16; s <<= 1) sm += __shfl_xor(sm, s);
            float inv = 1.0f / sm;
            *(hbf*)((char*)atb + swz128(n, 2 * col))        = f2b(p0 * inv);
            *(hbf*)((char*)atb + swz128(n, 2 * (16 + col))) = f2b(p1 * inv);
            *(hbf*)((char*)atb + swz128(n, 2 * (32 + col))) = f2b(p2 * inv);
            if (col == 0) *(hbf*)((char*)atb + swz128(n, 2 * 48)) = f2b(p3 * inv);
        }
        __syncthreads();   // atb ready

        // ---- PV (wave i owns out rows d = wave*16..+15) + fused epilogue ----
        short8 va0 = *(const short8*)((const char*)vbT + swz128(wave * 16 + col, quad * 16));
        short8 va1 = *(const short8*)((const char*)vbT + swz128(wave * 16 + col, 64 + quad * 16));
#pragma unroll
        for (int j = 0; j < 4; j++) {
            short8 pb0 = *(const short8*)((const char*)atb + swz128(nj[j], quad * 16));
            short8 pb1 = *(const short8*)((const char*)atb + swz128(nj[j], 64 + quad * 16));
            f32x4 o = (f32x4){0.f, 0.f, 0.f, 0.f};
            o = __builtin_amdgcn_mfma_f32_16x16x32_bf16(va0, pb0, o, 0, 0, 0);
            o = __builtin_amdgcn_mfma_f32_16x16x32_bf16(va1, pb1, o, 0, 0, 0);
            if (vj[j]) {
                size_t yo = ((size_t)w * 49 + nj[j]) * 512 + h * 64 + nq;
                *(unsigned*)(ywin + yo)     = pk2(hswish(o[0]), hswish(o[1]));
                *(unsigned*)(ywin + yo + 2) = pk2(hswish(o[2]), hswish(o[3]));
                if (h < 7) {   // next head input: pv + spx[h+1]
                    const float* ys = y2 + (size_t)((h + 1) * 64 + nq) * NPOS + base + posj[j];
                    unsigned s0 = pk2(o[0] + ys[0],
                                      o[1] + ys[(size_t)NPOS]);
                    unsigned s1 = pk2(o[2] + ys[2 * (size_t)NPOS],
                                      o[3] + ys[3 * (size_t)NPOS]);
                    *(unsigned*)((char*)spT + swz128(nj[j], 2 * nq))     = s0;
                    *(unsigned*)((char*)spT + swz128(nj[j], 2 * nq + 4)) = s1;
                }
            }
        }
    }
}

// ---------------------------------------------------------------------------

extern "C" void kernel_launch(void* const* d_in, const int* in_sizes, int n_in,
                              void* d_out, int out_size, void* d_ws, size_t ws_size,
                              hipStream_t stream) {
    const void* x = d_in[0];

    if (ws_size < NEL * 10 + (size_t)ARENA_TOT * 2) return;

    uint8_t* p = (uint8_t*)d_ws;
    hbf*   R0 = (hbf*)p;                          // NEL bf16
    hbf*   R1 = (hbf*)(p + NEL * 2);              // NEL*4 bytes
    float* R2 = (float*)(p + NEL * 6);            // NEL f32
    hbf*   arena = (hbf*)(p + NEL * 10);

    hbf*   y1t  = R0;
    hbf*   hid  = R1;
    float* y2f  = R2;
    hbf*   ywin = R0;
    float* x3f  = (float*)R1;
    float* x4f  = R2;
    hbf*   x4t  = R0;
    hbf*   hid2 = R1;

    CvtTable tab = {{
        { d_in[3],  OFF_W01,  524288 },  // ffn0_w1
        { d_in[5],  OFF_W02,  524288 },  // ffn0_w2
        { d_in[20], OFF_W11,  524288 },  // ffn1_w1
        { d_in[22], OFF_W12,  524288 },  // ffn1_w2
        { d_in[16], OFF_PW,   262144 },  // proj_w
        { d_in[7],  OFF_QKVW, 49152 },   // qkv_w
        { d_in[8],  OFF_QKVB, 768 },     // qkv_b
        { d_in[9],  OFF_W7,   784 },
        { d_in[10], OFF_B7,   16 },
        { d_in[11], OFF_W5,   400 },
        { d_in[12], OFF_B5,   16 },
        { d_in[13], OFF_W3,   864 },
        { d_in[14], OFF_B3,   96 },
        { d_in[15], OFF_AB,   392 },
        { d_in[1],  OFF_D0W,  4608 },
        { d_in[2],  OFF_D0B,  512 },
        { d_in[18], OFF_D1W,  4608 },
        { d_in[19], OFF_D1B,  512 },
        { d_in[4],  OFF_B01,  1024 },
        { d_in[6],  OFF_B02,  512 },
        { d_in[21], OFF_B11,  1024 },
        { d_in[23], OFF_B12,  512 },
        { d_in[17], OFF_PB,   512 },
    }};

    dim3 blk(256);

    // 0. convert all weights/biases to bf16 arena
    k_convert<<<dim3(2048, 23), blk, 0, stream>>>(tab, arena, x);
    // 1. y1t = (x + dw0(x)) NK bf16
    k_dw<0><<<dim3(NPOS / 64, 8), blk, 0, stream>>>(x, arena + OFF_D0W, arena + OFF_D0B, y1t, nullptr, x);
    // 2. hid = hswish(y1t @ ffn0_w1^T)  NK bf16 [NPOS][1024]  (SWAP grid: A once)
    k_gemm<0, 512, 8, true><<<dim3(8, 392), blk, 0, stream>>>(y1t, arena + OFF_W01, arena + OFF_B01, nullptr, hid, x);
    // 3. y2f = y1 + hid @ ffn0_w2^T  CT f32
    k_gemm<1, 1024, 4, false><<<dim3(4, 392), blk, 0, stream>>>(arena + OFF_W02, hid, arena + OFF_B02, y1t, y2f, x);
    // 4. attention -> ywin NK bf16 (hswish applied)
    k_attn<<<1024, blk, 0, stream>>>(y2f, arena, ywin);
    // 5. x3f = y2 + merge(ywin @ proj_w^T)  CT f32
    k_gemm<2, 512, 4, false><<<dim3(4, 392), blk, 0, stream>>>(arena + OFF_PW, ywin, arena + OFF_PB, y2f, x3f, x);
    // 6. x4f CT f32 + x4t NK bf16 = x3 + dw1(x3)
    k_dw<1><<<dim3(NPOS / 64, 8), blk, 0, stream>>>(x3f, arena + OFF_D1W, arena + OFF_D1B, x4t, x4f, x);
    // 7. hid2 = hswish(x4t @ ffn1_w1^T)  (SWAP grid: A once)
    k_gemm<0, 512, 8, true><<<dim3(8, 392), blk, 0, stream>>>(x4t, arena + OFF_W11, arena + OFF_B11, nullptr, hid2, x);
    // 8. out = x4 + hid2 @ ffn1_w2^T  NCHW (dtype per probe)
    k_gemm<3, 1024, 4, false><<<dim3(4, 392), blk, 0, stream>>>(arena + OFF_W12, hid2, arena + OFF_B12, x4f, d_out, x);
}